// Round 5
// baseline (650.003 us; speedup 1.0000x reference)
//
#include <hip/hip_runtime.h>

#define NN 50000
#define D 256
#define NQ 128
#define PG 256
#define NE 32768
#define ME 64
#define BCAP 32
#define KDIM 256
#define NKT 8

typedef _Float16 f16;
typedef __attribute__((ext_vector_type(4))) _Float16 f16x4;
typedef __attribute__((ext_vector_type(8))) _Float16 f16x8;
typedef __attribute__((ext_vector_type(4))) float f32x4;

#define MFMA16(a,b,c) __builtin_amdgcn_mfma_f32_16x16x32_f16(a,b,c,0,0,0)

__device__ __forceinline__ unsigned fenc(float f){
  unsigned b = __float_as_uint(f);
  return (b & 0x80000000u) ? ~b : (b | 0x80000000u);
}
__device__ __forceinline__ float fdec(unsigned u){
  unsigned b = (u & 0x80000000u) ? (u & 0x7fffffffu) : ~u;
  return __uint_as_float(b);
}
__device__ __forceinline__ void split8(float4 a, float4 b, f16x8& h, f16x8& l){
  float v[8] = {a.x,a.y,a.z,a.w,b.x,b.y,b.z,b.w};
#pragma unroll
  for (int i=0;i<8;++i){
    _Float16 hh = (_Float16)v[i];
    h[i] = hh;
    l[i] = (_Float16)(v[i] - (float)hh);
  }
}

// ---------- fp16x3 MFMA GEMM: C(f32) = A_f32(M x 256) @ (Bh+Bl)^T -----------
// A is fp32; split into (Ah+Al) in-register during LDS staging (same global
// bytes as pre-split f16 pair). BT is N x 256 row-major pre-split f16.
template<int EPI>
__global__ __launch_bounds__(256) void hgemm(const float* __restrict__ A,
                                             int Mrows,
                                             const f16* __restrict__ Bh, const f16* __restrict__ Bl,
                                             float* __restrict__ C, int ldc,
                                             const float* __restrict__ bias)
{
  __shared__ f16 AsH[128*40], AsL[128*40], BsH[128*40], BsL[128*40];
  const int tid = threadIdx.x;
  const int rb = blockIdx.x*128, cb = blockIdx.y*128;
  const int row = tid >> 1, ko = (tid & 1)*16;
  const bool aok = (rb + row) < Mrows;
  const int lane = tid & 63, wv = tid >> 6;
  const int qrw = (wv & 1)*64, qcw = (wv >> 1)*64;
  const int lm = lane & 15, qd = lane >> 4;

  const float* gA = A + (size_t)(rb+row)*KDIM + ko;
  const f16* gBh = Bh + (size_t)(cb+row)*KDIM + ko;
  const f16* gBl = Bl + (size_t)(cb+row)*KDIM + ko;

  float4 pa0=make_float4(0.f,0.f,0.f,0.f), pa1=pa0, pa2=pa0, pa3=pa0;
  f16x8 pbh0, pbh1, pbl0, pbl1;
  if (aok){ pa0 = *(const float4*)gA;     pa1 = *(const float4*)(gA+4);
            pa2 = *(const float4*)(gA+8); pa3 = *(const float4*)(gA+12); }
  pbh0 = *(const f16x8*)gBh; pbh1 = *(const f16x8*)(gBh+8);
  pbl0 = *(const f16x8*)gBl; pbl1 = *(const f16x8*)(gBl+8);

  f32x4 acc[4][4];
#pragma unroll
  for (int t=0;t<4;++t)
#pragma unroll
    for (int u=0;u<4;++u)
#pragma unroll
      for (int r=0;r<4;++r) acc[t][u][r] = 0.f;

  const int wbase = row*40 + ko;
  for (int kt = 0; kt < NKT; ++kt){
    __syncthreads();
    {
      f16x8 h0,h1,l0,l1;
      split8(pa0,pa1,h0,l0); split8(pa2,pa3,h1,l1);
      *(f16x8*)(AsH + wbase) = h0; *(f16x8*)(AsH + wbase + 8) = h1;
      *(f16x8*)(AsL + wbase) = l0; *(f16x8*)(AsL + wbase + 8) = l1;
      *(f16x8*)(BsH + wbase) = pbh0; *(f16x8*)(BsH + wbase + 8) = pbh1;
      *(f16x8*)(BsL + wbase) = pbl0; *(f16x8*)(BsL + wbase + 8) = pbl1;
    }
    __syncthreads();
    if (kt+1 < NKT){
      const int k0 = (kt+1)*32;
      if (aok){ pa0 = *(const float4*)(gA + k0);     pa1 = *(const float4*)(gA + k0 + 4);
                pa2 = *(const float4*)(gA + k0 + 8); pa3 = *(const float4*)(gA + k0 + 12); }
      pbh0 = *(const f16x8*)(gBh + k0); pbh1 = *(const f16x8*)(gBh + k0 + 8);
      pbl0 = *(const f16x8*)(gBl + k0); pbl1 = *(const f16x8*)(gBl + k0 + 8);
    }
    f16x8 fah[4], fal[4], fbh[4], fbl[4];
#pragma unroll
    for (int t=0;t<4;++t){
      int off = (qrw + t*16 + lm)*40 + qd*8;
      fah[t] = *(const f16x8*)(AsH + off);
      fal[t] = *(const f16x8*)(AsL + off);
    }
#pragma unroll
    for (int u=0;u<4;++u){
      int off = (qcw + u*16 + lm)*40 + qd*8;
      fbh[u] = *(const f16x8*)(BsH + off);
      fbl[u] = *(const f16x8*)(BsL + off);
    }
#pragma unroll
    for (int t=0;t<4;++t)
#pragma unroll
      for (int u=0;u<4;++u){
        acc[t][u] = MFMA16(fah[t], fbh[u], acc[t][u]);
        acc[t][u] = MFMA16(fah[t], fbl[u], acc[t][u]);
        acc[t][u] = MFMA16(fal[t], fbh[u], acc[t][u]);
      }
  }
#pragma unroll
  for (int t=0;t<4;++t){
#pragma unroll
    for (int u=0;u<4;++u){
      int col = cb + qcw + u*16 + lm;
      f32x4 v = acc[t][u];
#pragma unroll
      for (int r=0;r<4;++r){
        int rg = rb + qrw + t*16 + qd*4 + r;
        if (rg < Mrows){
          float x = v[r];
          if (EPI==1){ x += bias[col]; x = x > 0.f ? x : 0.01f*x; }
          C[(size_t)rg*ldc + col] = x;
        }
      }
    }
  }
}

// ---- rel GEMM with fused logits epilogue: partial = sum_j C[e][j]*X[e][j] ---
// A (rel) fp32, split in-register. grid (256, 6): by 0,1 -> X=H[src];
// 2,3 -> H[dst]; 4,5 -> rel[e].
__global__ __launch_bounds__(256) void hgemm_rel(const float* __restrict__ A,
                                                 const f16* __restrict__ Bh, const f16* __restrict__ Bl,
                                                 const int* __restrict__ edges,
                                                 const float* __restrict__ H,
                                                 const float* __restrict__ Rel,
                                                 float* __restrict__ logits)
{
  __shared__ f16 AsH[128*40], AsL[128*40], BsH[128*40], BsL[128*40];
  __shared__ int sIdx[128];
  const int tid = threadIdx.x;
  const int rb = blockIdx.x*128, cb = blockIdx.y*128;
  const int sec = blockIdx.y >> 1;
  const int row = tid >> 1, ko = (tid & 1)*16;
  const int lane = tid & 63, wv = tid >> 6;
  const int qrw = (wv & 1)*64, qcw = (wv >> 1)*64;
  const int lm = lane & 15, qd = lane >> 4;

  if (tid < 128){
    int e = rb + tid;
    sIdx[tid] = (sec==0) ? edges[(size_t)e*8+6] : (sec==1 ? edges[(size_t)e*8+7] : 0);
  }

  const float* gA = A + (size_t)(rb+row)*KDIM + ko;
  const f16* gBh = Bh + (size_t)(cb+row)*KDIM + ko;
  const f16* gBl = Bl + (size_t)(cb+row)*KDIM + ko;

  float4 pa0 = *(const float4*)gA,     pa1 = *(const float4*)(gA+4);
  float4 pa2 = *(const float4*)(gA+8), pa3 = *(const float4*)(gA+12);
  f16x8 pbh0 = *(const f16x8*)gBh, pbh1 = *(const f16x8*)(gBh+8);
  f16x8 pbl0 = *(const f16x8*)gBl, pbl1 = *(const f16x8*)(gBl+8);

  f32x4 acc[4][4];
#pragma unroll
  for (int t=0;t<4;++t)
#pragma unroll
    for (int u=0;u<4;++u)
#pragma unroll
      for (int r=0;r<4;++r) acc[t][u][r] = 0.f;

  const int wbase = row*40 + ko;
  for (int kt = 0; kt < NKT; ++kt){
    __syncthreads();
    {
      f16x8 h0,h1,l0,l1;
      split8(pa0,pa1,h0,l0); split8(pa2,pa3,h1,l1);
      *(f16x8*)(AsH + wbase) = h0; *(f16x8*)(AsH + wbase + 8) = h1;
      *(f16x8*)(AsL + wbase) = l0; *(f16x8*)(AsL + wbase + 8) = l1;
      *(f16x8*)(BsH + wbase) = pbh0; *(f16x8*)(BsH + wbase + 8) = pbh1;
      *(f16x8*)(BsL + wbase) = pbl0; *(f16x8*)(BsL + wbase + 8) = pbl1;
    }
    __syncthreads();
    if (kt+1 < NKT){
      const int k0 = (kt+1)*32;
      pa0 = *(const float4*)(gA + k0);     pa1 = *(const float4*)(gA + k0 + 4);
      pa2 = *(const float4*)(gA + k0 + 8); pa3 = *(const float4*)(gA + k0 + 12);
      pbh0 = *(const f16x8*)(gBh + k0); pbh1 = *(const f16x8*)(gBh + k0 + 8);
      pbl0 = *(const f16x8*)(gBl + k0); pbl1 = *(const f16x8*)(gBl + k0 + 8);
    }
    f16x8 fah[4], fal[4], fbh[4], fbl[4];
#pragma unroll
    for (int t=0;t<4;++t){
      int off = (qrw + t*16 + lm)*40 + qd*8;
      fah[t] = *(const f16x8*)(AsH + off);
      fal[t] = *(const f16x8*)(AsL + off);
    }
#pragma unroll
    for (int u=0;u<4;++u){
      int off = (qcw + u*16 + lm)*40 + qd*8;
      fbh[u] = *(const f16x8*)(BsH + off);
      fbl[u] = *(const f16x8*)(BsL + off);
    }
#pragma unroll
    for (int t=0;t<4;++t)
#pragma unroll
      for (int u=0;u<4;++u){
        acc[t][u] = MFMA16(fah[t], fbh[u], acc[t][u]);
        acc[t][u] = MFMA16(fah[t], fbl[u], acc[t][u]);
        acc[t][u] = MFMA16(fal[t], fbh[u], acc[t][u]);
      }
  }
  const int cbase = ((blockIdx.y & 1)*128) + qcw + lm;
#pragma unroll
  for (int t=0;t<4;++t){
#pragma unroll
    for (int r=0;r<4;++r){
      int lrow = qrw + t*16 + qd*4 + r;
      int e = rb + lrow;
      const float* xb = (sec==2) ? (Rel + (size_t)e*256)
                                 : (H + (size_t)sIdx[lrow]*256);
      float p = acc[t][0][r]*xb[cbase]
              + acc[t][1][r]*xb[cbase+16]
              + acc[t][2][r]*xb[cbase+32]
              + acc[t][3][r]*xb[cbase+48];
      p += __shfl_xor(p, 1); p += __shfl_xor(p, 2);
      p += __shfl_xor(p, 4); p += __shfl_xor(p, 8);
      if (lm == 0) atomicAdd(logits + e, p);
    }
  }
}

// ---------------- fp16 split helper (small matrices only) -------------------
__global__ void split_f16(const float* __restrict__ X, f16* __restrict__ Xh,
                          f16* __restrict__ Xl, int n)
{
  int i = (blockIdx.x*256 + threadIdx.x)*4;
  if (i >= n) return;
  float4 v = *(const float4*)(X+i);
  f16x4 h, l;
  h[0]=(_Float16)v.x; h[1]=(_Float16)v.y; h[2]=(_Float16)v.z; h[3]=(_Float16)v.w;
  l[0]=(_Float16)(v.x-(float)h[0]); l[1]=(_Float16)(v.y-(float)h[1]);
  l[2]=(_Float16)(v.z-(float)h[2]); l[3]=(_Float16)(v.w-(float)h[3]);
  *(f16x4*)(Xh+i)=h; *(f16x4*)(Xl+i)=l;
}

__global__ void build_bt_mhh(const float* __restrict__ M, f16* __restrict__ Bh, f16* __restrict__ Bl)
{
  int idx = blockIdx.x*256 + threadIdx.x;   // 65536: BT[n][k] = M_hh[k][n]
  int n = idx >> 8, k = idx & 255;
  float v = M[(size_t)k*1024 + n];
  _Float16 h = (_Float16)v;
  Bh[idx] = h; Bl[idx] = (_Float16)(v - (float)h);
}

__global__ void build_bt_wcat(const float* __restrict__ M, f16* __restrict__ Bh, f16* __restrict__ Bl)
{
  int idx = blockIdx.x*256 + threadIdx.x;   // 196608: BT[j][k] = Wcat[k][j]
  int j = idx >> 8, k = idx & 255;
  float v;
  if (j < 256)      v = M[(size_t)j*1024 + 256 + k];            // a1 = M_hr^T
  else if (j < 512) v = M[(size_t)(256+k)*1024 + (j-256)];      // a2 = M_rh
  else              v = M[(size_t)(256 + j-512)*1024 + 256 + k];// a3 = M_rr^T
  _Float16 h = (_Float16)v;
  Bh[idx] = h; Bl[idx] = (_Float16)(v - (float)h);
}

// ------- M = Wq^T @ Wk (1024x1024), fp64, fused K-split reduction -----------
// Bit-identical numerics to gemm_tn_split(z=8) + reduce_m: per z-block of
// K=128 (8 slabs of 16), acc accumulates slab/jj ascending; at each z
// boundary tot += acc (z ascending, tot starts 0.0) — exactly reduce_m's
// s = ((0+p0)+p1)+... order. Round once to f32 at the end. No 64 MB fp64
// partial round-trip, no reduce_m launch.
// Shape: 64x64 tile/block, 4x4 acc/thread (32 VGPR acc + 32 VGPR tot),
// grouped stride-10 LDS layout (r4-validated, conflict-free).
__global__ __launch_bounds__(256) void gemm_tn_full(const float* __restrict__ A,
                                                    const float* __restrict__ B,
                                                    float* __restrict__ Mout)
{
  // column c in [0,64) -> LDS offset (c>>3)*10 + (c&7) doubles; row stride 82
  __shared__ __align__(16) double As[16*82];
  __shared__ __align__(16) double Bs[16*82];
  const int tid = threadIdx.x;
  const int rb = blockIdx.x * 64, cb = blockIdx.y * 64;
  const int ty = tid >> 4, tx = tid & 15;       // compute: 16x16 grid, 4x4 each
  const int aj = tid >> 4, ag = tid & 15;       // staging: row aj, 4-col chunk ag
  double acc[4][4] = {};
  double tot[4][4] = {};

  const float* gA = A + (size_t)aj*1024 + rb + ag*4;
  const float* gB = B + (size_t)aj*1024 + cb + ag*4;
  float4 av = *(const float4*)gA;
  float4 bv = *(const float4*)gB;

  const int wbase = aj*82 + (ag>>1)*10 + (ag&1)*4;
  const int aoff  = (ty>>1)*10 + (ty&1)*4;
  const int boff  = (tx>>1)*10 + (tx&1)*4;

  for (int slab = 0; slab < 64; ++slab) {
    __syncthreads();
    {
      double2* wa = (double2*)(As + wbase);
      double2* wb = (double2*)(Bs + wbase);
      wa[0] = make_double2((double)av.x, (double)av.y);
      wa[1] = make_double2((double)av.z, (double)av.w);
      wb[0] = make_double2((double)bv.x, (double)bv.y);
      wb[1] = make_double2((double)bv.z, (double)bv.w);
    }
    __syncthreads();
    if (slab < 63){
      gA += 16*1024; gB += 16*1024;
      av = *(const float4*)gA;
      bv = *(const float4*)gB;
    }
#pragma unroll
    for (int jj=0; jj<16; ++jj){
      const double* pa = As + jj*82 + aoff;
      const double* pb = Bs + jj*82 + boff;
      double2 a01 = *(const double2*)(pa);
      double2 a23 = *(const double2*)(pa+2);
      double2 b01 = *(const double2*)(pb);
      double2 b23 = *(const double2*)(pb+2);
      double a0=a01.x, a1=a01.y, a2=a23.x, a3=a23.y;
      double b0=b01.x, b1=b01.y, b2=b23.x, b3=b23.y;
      acc[0][0]+=a0*b0; acc[0][1]+=a0*b1; acc[0][2]+=a0*b2; acc[0][3]+=a0*b3;
      acc[1][0]+=a1*b0; acc[1][1]+=a1*b1; acc[1][2]+=a1*b2; acc[1][3]+=a1*b3;
      acc[2][0]+=a2*b0; acc[2][1]+=a2*b1; acc[2][2]+=a2*b2; acc[2][3]+=a2*b3;
      acc[3][0]+=a3*b0; acc[3][1]+=a3*b1; acc[3][2]+=a3*b2; acc[3][3]+=a3*b3;
    }
    if ((slab & 7) == 7){                       // z-block boundary: fold partial
#pragma unroll
      for (int i=0;i<4;++i)
#pragma unroll
        for (int j=0;j<4;++j){ tot[i][j] += acc[i][j]; acc[i][j] = 0.0; }
    }
  }
#pragma unroll
  for (int i=0;i<4;++i)
#pragma unroll
    for (int j=0;j<4;++j)
      Mout[(size_t)(rb+ty*4+i)*1024 + cb+tx*4+j] = (float)tot[i][j];
}

// ---------------- query tables as GEMM --------------------------------------
__global__ void build_g(const float* __restrict__ qst, const float* __restrict__ qr,
                        float* __restrict__ G)
{
  int idx = blockIdx.x*256 + threadIdx.x;   // 65536
  int q = idx >> 9, k = idx & 511;
  G[idx] = (k < 256) ? qst[(size_t)q*256 + k] : qr[(size_t)q*256 + k - 256];
}

// Bq (512 x 1280): cols [qt1-proj | qt2-proj | qw-proj | M_gg]
__global__ void build_bq(const float* __restrict__ M, float* __restrict__ Bq)
{
  int idx = blockIdx.x*256 + threadIdx.x;   // 655360
  int k = idx / 1280, t = idx - k*1280;
  float v;
  if (t < 256)      v = M[(size_t)t*1024 + 512 + k];
  else if (t < 512) v = M[(size_t)(512+k)*1024 + (t-256)];
  else if (t < 768) v = M[(size_t)(256+(t-512))*1024 + 512 + k]
                      + M[(size_t)(512+k)*1024 + 256 + (t-512)];
  else              v = M[(size_t)(512+k)*1024 + 512 + (t-768)];
  Bq[idx] = v;
}

// fp32 GEMM 64x64 tile, conflict-aware, prefetch (for the tiny qtab product)
__global__ __launch_bounds__(256) void gemm64(const float* __restrict__ A, int lda,
                                              const float* __restrict__ B, int ldb,
                                              float* __restrict__ C, int ldc,
                                              int Mrows, int Kdim)
{
  __shared__ float As[16][68];
  __shared__ float Bs[16][68];
  const int tid = threadIdx.x;
  const int rb = blockIdx.x*64, cb = blockIdx.y*64;
  const int tx = tid & 15, ty = tid >> 4;
  const int a_r = tid >> 2, a_k = (tid & 3)*4;
  const int b_c = tid & 63, b_r0 = (tid >> 6)*4;
  const bool aok = (rb + a_r) < Mrows;
  float4 pa = make_float4(0.f,0.f,0.f,0.f);
  float pb[4];
  if (aok) pa = *(const float4*)(A + (size_t)(rb+a_r)*lda + a_k);
#pragma unroll
  for (int j=0;j<4;++j) pb[j] = B[(size_t)(b_r0+j)*ldb + cb + b_c];
  float acc[4][4] = {};
  const int NK = Kdim >> 4;
  for (int t0=0; t0<NK; ++t0){
    __syncthreads();
    As[a_k+0][a_r]=pa.x; As[a_k+1][a_r]=pa.y; As[a_k+2][a_r]=pa.z; As[a_k+3][a_r]=pa.w;
#pragma unroll
    for (int j=0;j<4;++j) Bs[b_r0+j][b_c] = pb[j];
    __syncthreads();
    if (t0+1 < NK){
      int k0 = (t0+1) << 4;
      if (aok) pa = *(const float4*)(A + (size_t)(rb+a_r)*lda + k0 + a_k);
#pragma unroll
      for (int j=0;j<4;++j) pb[j] = B[(size_t)(k0+b_r0+j)*ldb + cb + b_c];
    }
#pragma unroll
    for (int kk=0;kk<16;++kk){
      float a[4], b[4];
      *(float4*)&a[0] = *(const float4*)&As[kk][ty*4];
#pragma unroll
      for (int j=0;j<4;++j) b[j] = Bs[kk][tx + 16*j];
#pragma unroll
      for (int i=0;i<4;++i)
#pragma unroll
        for (int j=0;j<4;++j) acc[i][j] += a[i]*b[j];
    }
  }
#pragma unroll
  for (int i=0;i<4;++i){
    int r = rb + ty*4 + i;
    if (r < Mrows)
#pragma unroll
      for (int j=0;j<4;++j)
        C[(size_t)r*ldc + cb + tx + 16*j] = acc[i][j];
  }
}

__global__ __launch_bounds__(256) void qc_dot(const float* __restrict__ Ccat,
    const float* __restrict__ qst, const float* __restrict__ qr, float* __restrict__ qc)
{
  __shared__ float red[256];
  int q = blockIdx.x, t = threadIdx.x;
  float a = Ccat[(size_t)q*1280 + 768 + t]  * qst[(size_t)q*256 + t]
          + Ccat[(size_t)q*1280 + 1024 + t] * qr [(size_t)q*256 + t];
  red[t] = a;
  __syncthreads();
  for (int s=128; s>0; s>>=1){
    if (t < s) red[t] += red[t+s];
    __syncthreads();
  }
  if (t==0) qc[q] = red[0];
}

// ---------------- slim per-edge logits (non-g terms) ------------------------
__global__ __launch_bounds__(256) void slim_logits(const int* __restrict__ edges,
    const float* __restrict__ H, const float* __restrict__ U,
    const float* __restrict__ Rel,
    const float* __restrict__ Ct, const float* __restrict__ qc,
    float* __restrict__ logits)
{
  int lane = threadIdx.x & 63;
  int e = blockIdx.x*4 + (threadIdx.x >> 6);
  int q   = edges[(size_t)e*8 + 0];
  int src = edges[(size_t)e*8 + 6];
  int dst = edges[(size_t)e*8 + 7];
  const float4* hs = (const float4*)(H   + (size_t)src*256);
  const float4* hd = (const float4*)(H   + (size_t)dst*256);
  const float4* us = (const float4*)(U   + (size_t)src*256);
  const float4* rl = (const float4*)(Rel + (size_t)e*256);
  const float4* t1 = (const float4*)(Ct + (size_t)q*1280);
  const float4* t2 = (const float4*)(Ct + (size_t)q*1280 + 256);
  const float4* w4 = (const float4*)(Ct + (size_t)q*1280 + 512);
  float4 a, b, c;
  float s = 0.f;
  a = hd[lane]; b = us[lane]; c = t2[lane];
  s += a.x*(b.x+c.x) + a.y*(b.y+c.y) + a.z*(b.z+c.z) + a.w*(b.w+c.w);
  a = hs[lane]; c = t1[lane];
  s += a.x*c.x + a.y*c.y + a.z*c.z + a.w*c.w;
  a = rl[lane]; c = w4[lane];
  s += a.x*c.x + a.y*c.y + a.z*c.z + a.w*c.w;
#pragma unroll
  for (int off=32; off>0; off>>=1) s += __shfl_down(s, off);
  if (lane==0) logits[e] = s + qc[q];
}

// ---------------- segmented softmax over src-node segments ------------------
__global__ void segmax_k(const int* __restrict__ edges, const float* __restrict__ logits,
                         unsigned* __restrict__ menc, int nE)
{
  int e = blockIdx.x*256 + threadIdx.x; if (e >= nE) return;
  atomicMax(menc + edges[(size_t)e*8+6], fenc(logits[e]));
}
__global__ void segexp_k(const int* __restrict__ edges, const float* __restrict__ logits,
                         const unsigned* __restrict__ menc, float* __restrict__ ebuf,
                         float* __restrict__ ssum, int nE)
{
  int e = blockIdx.x*256 + threadIdx.x; if (e >= nE) return;
  int s = edges[(size_t)e*8+6];
  float ex = expf(logits[e] - fdec(menc[s]));
  ebuf[e] = ex;
  atomicAdd(ssum + s, ex);
}
template<int TGT>
__global__ void segsoft_k(const int* __restrict__ edges, const float* __restrict__ ebuf,
                          const float* __restrict__ ssum, float* __restrict__ soft,
                          const float* __restrict__ score, float* __restrict__ target, int nE)
{
  int e = blockIdx.x*256 + threadIdx.x; if (e >= nE) return;
  int s = edges[(size_t)e*8+6];
  float so = ebuf[e] / ssum[s];
  soft[e] = so;
  if (TGT) target[e] = so * score[s];
}

// ---------------- per-query top-64 (bitonic, matches top_k tie order) -------
__global__ __launch_bounds__(256) void topk_k(const float* __restrict__ target,
    const float* __restrict__ soft, const int* __restrict__ edges1,
    float* __restrict__ out0, float* __restrict__ out2, float* __restrict__ out3,
    int* __restrict__ p_src, int* __restrict__ p_dst, float* __restrict__ p_w)
{
  int qb = blockIdx.x, t = threadIdx.x;
  __shared__ float v[256];
  __shared__ int   ix[256];
  v[t] = target[(size_t)qb*256 + t];
  ix[t] = t;
  __syncthreads();
  for (int k=2; k<=256; k<<=1){
    for (int j=k>>1; j>0; j>>=1){
      int ixj = t ^ j;
      if (ixj > t){
        float va=v[t], vb=v[ixj]; int ia=ix[t], ib=ix[ixj];
        bool dir  = ((t & k) == 0);
        bool l_ab = (va > vb) || (va == vb && ia < ib);
        bool sw   = dir ? (!l_ab) : l_ab;
        if (sw){ v[t]=vb; v[ixj]=va; ix[t]=ib; ix[ixj]=ia; }
      }
      __syncthreads();
    }
  }
  if (t < 64){
    int oi = qb*256 + ix[t];
    int o  = qb*64 + t;
    out3[o] = (float)oi;
#pragma unroll
    for (int c2=0;c2<8;++c2) out2[(size_t)o*8 + c2] = (float)edges1[(size_t)oi*8 + c2];
    int s_ = edges1[(size_t)oi*8+6], d_ = edges1[(size_t)oi*8+7];
    p_src[o] = s_; p_dst[o] = d_; p_w[o] = soft[oi];
    atomicAdd(out0 + d_, v[t]);
  }
}

// ---------------- bucketized repr update ------------------------------------
__global__ void bucket_fill(const int* __restrict__ srcarr, int stride, int n,
                            int* __restrict__ counts, int* __restrict__ bucket,
                            int* __restrict__ over, int* __restrict__ n_over)
{
  int e = blockIdx.x*256 + threadIdx.x; if (e >= n) return;
  int s = srcarr[(size_t)e*stride];
  int pos = atomicAdd(counts + s, 1);
  if (pos < BCAP) bucket[(size_t)s*BCAP + pos] = e;
  else { int oi = atomicAdd(n_over, 1); over[oi] = e; }
}

__global__ __launch_bounds__(256) void fused_update(const int* __restrict__ counts,
    const int* __restrict__ bucket, const int* __restrict__ dstarr, int dstride,
    const float* __restrict__ w, const float* __restrict__ Hin, float* __restrict__ Hout)
{
  int lane = threadIdx.x & 63;
  int n = blockIdx.x*4 + (threadIdx.x >> 6);
  if (n >= NN) return;
  int cnt = counts[n];
  float fac = cnt > 0 ? 0.2f : 1.0f;
  float4 h = ((const float4*)(Hin + (size_t)n*256))[lane];
  float4 acc = make_float4(fac*h.x, fac*h.y, fac*h.z, fac*h.w);
  int m = cnt < BCAP ? cnt : BCAP;
  for (int i=0;i<m;++i){
    int e = bucket[(size_t)n*BCAP + i];
    int d = dstarr[(size_t)e*dstride];
    float f = 0.8f * w[e];
    float4 vv = ((const float4*)(Hin + (size_t)d*256))[lane];
    acc.x += f*vv.x; acc.y += f*vv.y; acc.z += f*vv.z; acc.w += f*vv.w;
  }
  ((float4*)(Hout + (size_t)n*256))[lane] = acc;
}

__global__ __launch_bounds__(256) void over_k(const int* __restrict__ over,
    const int* __restrict__ n_over,
    const int* __restrict__ srcarr, int sstride,
    const int* __restrict__ dstarr, int dstride,
    const float* __restrict__ w, const float* __restrict__ Hin, float* __restrict__ Hout)
{
  int lane = threadIdx.x & 63;
  int i = blockIdx.x*4 + (threadIdx.x >> 6);
  if (i >= *n_over) return;
  int e = over[i];
  int s = srcarr[(size_t)e*sstride], d = dstarr[(size_t)e*dstride];
  float f = 0.8f * w[e];
  float4 vv = ((const float4*)(Hin + (size_t)d*256))[lane];
  float* o = Hout + (size_t)s*256 + lane*4;
  atomicAdd(o+0, f*vv.x); atomicAdd(o+1, f*vv.y);
  atomicAdd(o+2, f*vv.z); atomicAdd(o+3, f*vv.w);
}

// ---------------- host launch ------------------------------------------------
extern "C" void kernel_launch(void* const* d_in, const int* in_sizes, int n_in,
                              void* d_out, int out_size, void* d_ws, size_t ws_size,
                              hipStream_t stream)
{
  const float* score = (const float*)d_in[0];
  const float* H0    = (const float*)d_in[1];
  const int*   edges0= (const int*)d_in[2];
  const int*   edges1= (const int*)d_in[3];
  const float* rel0  = (const float*)d_in[4];
  const float* rel1  = (const float*)d_in[5];
  const float* qst   = (const float*)d_in[6];
  const float* qr    = (const float*)d_in[7];
  const float* Wq    = (const float*)d_in[8];
  const float* Wk    = (const float*)d_in[9];
  const float* Wl    = (const float*)d_in[10];
  const float* bl    = (const float*)d_in[11];
  (void)in_sizes; (void)n_in; (void)out_size; (void)ws_size;

  float* out0 = (float*)d_out;
  float* out1 = out0 + NN;
  float* out2 = out1 + (size_t)NN*D;
  float* out3 = out2 + (size_t)NQ*ME*8;

  float* ws     = (float*)d_ws;
  float* Mbuf   = ws;                          // 1,048,576
  float* Ccat   = ws + 1048576;                // 128x1280 = 163,840
  float* qcv    = ws + 1212416;                // 128
  float* G      = ws + 1212544;                // 65,536
  float* logits = ws + 1278080;                // 32,768
  float* ebuf   = ws + 1310848;
  float* soft   = ws + 1343616;
  float* target = ws + 1376384;
  unsigned* menc= (unsigned*)(ws + 1409152);   // 50,000
  float* ssum   = ws + 1459152;                // 50,000
  int* p_src    = (int*)(ws + 1509152);        // 8,192
  int* p_dst    = (int*)(ws + 1517344);
  float* p_w    = ws + 1525536;                // ends 1,533,728
  float* Bq     = ws + 1533728;                // 512x1280 = 655,360 -> 2,189,088
  float* U      = ws + 2189088;                // 12,800,000 -> 14,989,088
  float* Hnew   = ws + 14989088;               // 12,800,000 -> 27,789,088
  float* SCR    = ws + 27789088;
  int* counts = (int*)SCR;                     // 50,000
  int* n_over = (int*)(SCR + 50000);           // 1
  int* over   = (int*)(SCR + 50056);           // 32,768
  int* bucket = (int*)(SCR + 100000);          // 1,600,000 -> SCR+1,700,000
  float* P0   = SCR + 2000000;                 // = ws + 29,789,088
  f16* mhh_h  = (f16*)P0;                      // f16 staging area
  f16* mhh_l  = (f16*)(P0 + 32768);
  f16* wcat_h = (f16*)(P0 + 65536);
  f16* wcat_l = (f16*)(P0 + 163840);
  f16* wl_h   = (f16*)(P0 + 262144);
  f16* wl_l   = (f16*)(P0 + 294912);           // ends P0+327,680
  float* Hpre = U;                             // alias: U dead before Hpre written

  hipMemsetAsync(out0, 0, (size_t)NN*4, stream);
  hipMemsetAsync(menc, 0, (size_t)NN*4, stream);
  hipMemsetAsync(ssum, 0, (size_t)NN*4, stream);

  // setup: M (fp64, fused K-split reduction), query tables, f16 B builders
  gemm_tn_full<<<dim3(16,16), 256, 0, stream>>>(Wq, Wk, Mbuf);
  build_g<<<256, 256, 0, stream>>>(qst, qr, G);
  build_bq<<<2560, 256, 0, stream>>>(Mbuf, Bq);
  gemm64<<<dim3(2,20), 256, 0, stream>>>(G, 512, Bq, 1280, Ccat, 1280, NQ, 512);
  qc_dot<<<NQ, 256, 0, stream>>>(Ccat, qst, qr, qcv);
  build_bt_mhh<<<256, 256, 0, stream>>>(Mbuf, mhh_h, mhh_l);
  build_bt_wcat<<<768, 256, 0, stream>>>(Mbuf, wcat_h, wcat_l);
  split_f16<<<64, 256, 0, stream>>>(Wl, wl_h, wl_l, 65536);   // BT_wl == Wl

  // ---- call 1: edges1 / rel1 / H0 ----
  hgemm<0><<<dim3(391,2), 256, 0, stream>>>(H0, NN, mhh_h, mhh_l, U, 256, nullptr);
  slim_logits<<<NE/4, 256, 0, stream>>>(edges1, H0, U, rel1, Ccat, qcv, logits);
  hgemm_rel<<<dim3(256,6), 256, 0, stream>>>(rel1, wcat_h, wcat_l, edges1, H0, rel1, logits);

  segmax_k<<<NE/256, 256, 0, stream>>>(edges1, logits, menc, NE);
  segexp_k<<<NE/256, 256, 0, stream>>>(edges1, logits, menc, ebuf, ssum, NE);
  segsoft_k<1><<<NE/256, 256, 0, stream>>>(edges1, ebuf, ssum, soft, score, target, NE);

  topk_k<<<NQ, 256, 0, stream>>>(target, soft, edges1, out0, out2, out3, p_src, p_dst, p_w);

  hipMemsetAsync(counts, 0, (size_t)NN*4, stream);
  hipMemsetAsync(n_over, 0, 4, stream);
  bucket_fill<<<(NQ*ME+255)/256, 256, 0, stream>>>(p_src, 1, NQ*ME, counts, bucket, over, n_over);
  fused_update<<<(NN+3)/4, 256, 0, stream>>>(counts, bucket, p_dst, 1, p_w, H0, Hnew);
  over_k<<<(NQ*ME)/4, 256, 0, stream>>>(over, n_over, p_src, 1, p_dst, 1, p_w, H0, Hnew);

  hipMemsetAsync(menc, 0, (size_t)NN*4, stream);
  hipMemsetAsync(ssum, 0, (size_t)NN*4, stream);

  // ---- call 2: edges0 / rel0 / Hnew ----
  hgemm<0><<<dim3(391,2), 256, 0, stream>>>(Hnew, NN, mhh_h, mhh_l, U, 256, nullptr);
  slim_logits<<<NE/4, 256, 0, stream>>>(edges0, Hnew, U, rel0, Ccat, qcv, logits);
  hgemm_rel<<<dim3(256,6), 256, 0, stream>>>(rel0, wcat_h, wcat_l, edges0, Hnew, rel0, logits);

  segmax_k<<<NE/256, 256, 0, stream>>>(edges0, logits, menc, NE);
  segexp_k<<<NE/256, 256, 0, stream>>>(edges0, logits, menc, ebuf, ssum, NE);
  segsoft_k<0><<<NE/256, 256, 0, stream>>>(edges0, ebuf, ssum, soft, nullptr, nullptr, NE);

  hipMemsetAsync(counts, 0, (size_t)NN*4, stream);
  hipMemsetAsync(n_over, 0, 4, stream);
  bucket_fill<<<NE/256, 256, 0, stream>>>(edges0 + 6, 8, NE, counts, bucket, over, n_over);
  fused_update<<<(NN+3)/4, 256, 0, stream>>>(counts, bucket, edges0 + 7, 8, soft, Hnew, Hpre);
  over_k<<<NE/4, 256, 0, stream>>>(over, n_over, edges0 + 6, 8, edges0 + 7, 8, soft, Hnew, Hpre);

  // final: out1 = leaky_relu(Hpre @ Wl^T + bl)
  hgemm<1><<<dim3(391,2), 256, 0, stream>>>(Hpre, NN, wl_h, wl_l, out1, 256, bl);
}

// Round 6
// 618.900 us; speedup vs baseline: 1.0503x; 1.0503x over previous
//
#include <hip/hip_runtime.h>

#define NN 50000
#define D 256
#define NQ 128
#define PG 256
#define NE 32768
#define ME 64
#define BCAP 32
#define KDIM 256
#define NKT 8

typedef _Float16 f16;
typedef __attribute__((ext_vector_type(4))) _Float16 f16x4;
typedef __attribute__((ext_vector_type(8))) _Float16 f16x8;
typedef __attribute__((ext_vector_type(4))) float f32x4;

#define MFMA16(a,b,c) __builtin_amdgcn_mfma_f32_16x16x32_f16(a,b,c,0,0,0)

__device__ __forceinline__ unsigned fenc(float f){
  unsigned b = __float_as_uint(f);
  return (b & 0x80000000u) ? ~b : (b | 0x80000000u);
}
__device__ __forceinline__ float fdec(unsigned u){
  unsigned b = (u & 0x80000000u) ? (u & 0x7fffffffu) : ~u;
  return __uint_as_float(b);
}
__device__ __forceinline__ void split8(float4 a, float4 b, f16x8& h, f16x8& l){
  float v[8] = {a.x,a.y,a.z,a.w,b.x,b.y,b.z,b.w};
#pragma unroll
  for (int i=0;i<8;++i){
    _Float16 hh = (_Float16)v[i];
    h[i] = hh;
    l[i] = (_Float16)(v[i] - (float)hh);
  }
}

// ---------- fp16x3 MFMA GEMM: C(f32) = A_f32(M x 256) @ (Bh+Bl)^T -----------
// A is fp32; split into (Ah+Al) in-register during LDS staging (same global
// bytes as pre-split f16 pair). BT is N x 256 row-major pre-split f16.
template<int EPI>
__global__ __launch_bounds__(256) void hgemm(const float* __restrict__ A,
                                             int Mrows,
                                             const f16* __restrict__ Bh, const f16* __restrict__ Bl,
                                             float* __restrict__ C, int ldc,
                                             const float* __restrict__ bias)
{
  __shared__ f16 AsH[128*40], AsL[128*40], BsH[128*40], BsL[128*40];
  const int tid = threadIdx.x;
  const int rb = blockIdx.x*128, cb = blockIdx.y*128;
  const int row = tid >> 1, ko = (tid & 1)*16;
  const bool aok = (rb + row) < Mrows;
  const int lane = tid & 63, wv = tid >> 6;
  const int qrw = (wv & 1)*64, qcw = (wv >> 1)*64;
  const int lm = lane & 15, qd = lane >> 4;

  const float* gA = A + (size_t)(rb+row)*KDIM + ko;
  const f16* gBh = Bh + (size_t)(cb+row)*KDIM + ko;
  const f16* gBl = Bl + (size_t)(cb+row)*KDIM + ko;

  float4 pa0=make_float4(0.f,0.f,0.f,0.f), pa1=pa0, pa2=pa0, pa3=pa0;
  f16x8 pbh0, pbh1, pbl0, pbl1;
  if (aok){ pa0 = *(const float4*)gA;     pa1 = *(const float4*)(gA+4);
            pa2 = *(const float4*)(gA+8); pa3 = *(const float4*)(gA+12); }
  pbh0 = *(const f16x8*)gBh; pbh1 = *(const f16x8*)(gBh+8);
  pbl0 = *(const f16x8*)gBl; pbl1 = *(const f16x8*)(gBl+8);

  f32x4 acc[4][4];
#pragma unroll
  for (int t=0;t<4;++t)
#pragma unroll
    for (int u=0;u<4;++u)
#pragma unroll
      for (int r=0;r<4;++r) acc[t][u][r] = 0.f;

  const int wbase = row*40 + ko;
  for (int kt = 0; kt < NKT; ++kt){
    __syncthreads();
    {
      f16x8 h0,h1,l0,l1;
      split8(pa0,pa1,h0,l0); split8(pa2,pa3,h1,l1);
      *(f16x8*)(AsH + wbase) = h0; *(f16x8*)(AsH + wbase + 8) = h1;
      *(f16x8*)(AsL + wbase) = l0; *(f16x8*)(AsL + wbase + 8) = l1;
      *(f16x8*)(BsH + wbase) = pbh0; *(f16x8*)(BsH + wbase + 8) = pbh1;
      *(f16x8*)(BsL + wbase) = pbl0; *(f16x8*)(BsL + wbase + 8) = pbl1;
    }
    __syncthreads();
    if (kt+1 < NKT){
      const int k0 = (kt+1)*32;
      if (aok){ pa0 = *(const float4*)(gA + k0);     pa1 = *(const float4*)(gA + k0 + 4);
                pa2 = *(const float4*)(gA + k0 + 8); pa3 = *(const float4*)(gA + k0 + 12); }
      pbh0 = *(const f16x8*)(gBh + k0); pbh1 = *(const f16x8*)(gBh + k0 + 8);
      pbl0 = *(const f16x8*)(gBl + k0); pbl1 = *(const f16x8*)(gBl + k0 + 8);
    }
    f16x8 fah[4], fal[4], fbh[4], fbl[4];
#pragma unroll
    for (int t=0;t<4;++t){
      int off = (qrw + t*16 + lm)*40 + qd*8;
      fah[t] = *(const f16x8*)(AsH + off);
      fal[t] = *(const f16x8*)(AsL + off);
    }
#pragma unroll
    for (int u=0;u<4;++u){
      int off = (qcw + u*16 + lm)*40 + qd*8;
      fbh[u] = *(const f16x8*)(BsH + off);
      fbl[u] = *(const f16x8*)(BsL + off);
    }
#pragma unroll
    for (int t=0;t<4;++t)
#pragma unroll
      for (int u=0;u<4;++u){
        acc[t][u] = MFMA16(fah[t], fbh[u], acc[t][u]);
        acc[t][u] = MFMA16(fah[t], fbl[u], acc[t][u]);
        acc[t][u] = MFMA16(fal[t], fbh[u], acc[t][u]);
      }
  }
#pragma unroll
  for (int t=0;t<4;++t){
#pragma unroll
    for (int u=0;u<4;++u){
      int col = cb + qcw + u*16 + lm;
      f32x4 v = acc[t][u];
#pragma unroll
      for (int r=0;r<4;++r){
        int rg = rb + qrw + t*16 + qd*4 + r;
        if (rg < Mrows){
          float x = v[r];
          if (EPI==1){ x += bias[col]; x = x > 0.f ? x : 0.01f*x; }
          C[(size_t)rg*ldc + col] = x;
        }
      }
    }
  }
}

// ---- rel GEMM with fused logits epilogue: partial = sum_j C[e][j]*X[e][j] ---
// A (rel) fp32, split in-register. grid (256, 6): by 0,1 -> X=H[src];
// 2,3 -> H[dst]; 4,5 -> rel[e].
__global__ __launch_bounds__(256) void hgemm_rel(const float* __restrict__ A,
                                                 const f16* __restrict__ Bh, const f16* __restrict__ Bl,
                                                 const int* __restrict__ edges,
                                                 const float* __restrict__ H,
                                                 const float* __restrict__ Rel,
                                                 float* __restrict__ logits)
{
  __shared__ f16 AsH[128*40], AsL[128*40], BsH[128*40], BsL[128*40];
  __shared__ int sIdx[128];
  const int tid = threadIdx.x;
  const int rb = blockIdx.x*128, cb = blockIdx.y*128;
  const int sec = blockIdx.y >> 1;
  const int row = tid >> 1, ko = (tid & 1)*16;
  const int lane = tid & 63, wv = tid >> 6;
  const int qrw = (wv & 1)*64, qcw = (wv >> 1)*64;
  const int lm = lane & 15, qd = lane >> 4;

  if (tid < 128){
    int e = rb + tid;
    sIdx[tid] = (sec==0) ? edges[(size_t)e*8+6] : (sec==1 ? edges[(size_t)e*8+7] : 0);
  }

  const float* gA = A + (size_t)(rb+row)*KDIM + ko;
  const f16* gBh = Bh + (size_t)(cb+row)*KDIM + ko;
  const f16* gBl = Bl + (size_t)(cb+row)*KDIM + ko;

  float4 pa0 = *(const float4*)gA,     pa1 = *(const float4*)(gA+4);
  float4 pa2 = *(const float4*)(gA+8), pa3 = *(const float4*)(gA+12);
  f16x8 pbh0 = *(const f16x8*)gBh, pbh1 = *(const f16x8*)(gBh+8);
  f16x8 pbl0 = *(const f16x8*)gBl, pbl1 = *(const f16x8*)(gBl+8);

  f32x4 acc[4][4];
#pragma unroll
  for (int t=0;t<4;++t)
#pragma unroll
    for (int u=0;u<4;++u)
#pragma unroll
      for (int r=0;r<4;++r) acc[t][u][r] = 0.f;

  const int wbase = row*40 + ko;
  for (int kt = 0; kt < NKT; ++kt){
    __syncthreads();
    {
      f16x8 h0,h1,l0,l1;
      split8(pa0,pa1,h0,l0); split8(pa2,pa3,h1,l1);
      *(f16x8*)(AsH + wbase) = h0; *(f16x8*)(AsH + wbase + 8) = h1;
      *(f16x8*)(AsL + wbase) = l0; *(f16x8*)(AsL + wbase + 8) = l1;
      *(f16x8*)(BsH + wbase) = pbh0; *(f16x8*)(BsH + wbase + 8) = pbh1;
      *(f16x8*)(BsL + wbase) = pbl0; *(f16x8*)(BsL + wbase + 8) = pbl1;
    }
    __syncthreads();
    if (kt+1 < NKT){
      const int k0 = (kt+1)*32;
      pa0 = *(const float4*)(gA + k0);     pa1 = *(const float4*)(gA + k0 + 4);
      pa2 = *(const float4*)(gA + k0 + 8); pa3 = *(const float4*)(gA + k0 + 12);
      pbh0 = *(const f16x8*)(gBh + k0); pbh1 = *(const f16x8*)(gBh + k0 + 8);
      pbl0 = *(const f16x8*)(gBl + k0); pbl1 = *(const f16x8*)(gBl + k0 + 8);
    }
    f16x8 fah[4], fal[4], fbh[4], fbl[4];
#pragma unroll
    for (int t=0;t<4;++t){
      int off = (qrw + t*16 + lm)*40 + qd*8;
      fah[t] = *(const f16x8*)(AsH + off);
      fal[t] = *(const f16x8*)(AsL + off);
    }
#pragma unroll
    for (int u=0;u<4;++u){
      int off = (qcw + u*16 + lm)*40 + qd*8;
      fbh[u] = *(const f16x8*)(BsH + off);
      fbl[u] = *(const f16x8*)(BsL + off);
    }
#pragma unroll
    for (int t=0;t<4;++t)
#pragma unroll
      for (int u=0;u<4;++u){
        acc[t][u] = MFMA16(fah[t], fbh[u], acc[t][u]);
        acc[t][u] = MFMA16(fah[t], fbl[u], acc[t][u]);
        acc[t][u] = MFMA16(fal[t], fbh[u], acc[t][u]);
      }
  }
  const int cbase = ((blockIdx.y & 1)*128) + qcw + lm;
#pragma unroll
  for (int t=0;t<4;++t){
#pragma unroll
    for (int r=0;r<4;++r){
      int lrow = qrw + t*16 + qd*4 + r;
      int e = rb + lrow;
      const float* xb = (sec==2) ? (Rel + (size_t)e*256)
                                 : (H + (size_t)sIdx[lrow]*256);
      float p = acc[t][0][r]*xb[cbase]
              + acc[t][1][r]*xb[cbase+16]
              + acc[t][2][r]*xb[cbase+32]
              + acc[t][3][r]*xb[cbase+48];
      p += __shfl_xor(p, 1); p += __shfl_xor(p, 2);
      p += __shfl_xor(p, 4); p += __shfl_xor(p, 8);
      if (lm == 0) atomicAdd(logits + e, p);
    }
  }
}

// ---------------- fp16 split helper (small matrices only) -------------------
__global__ void split_f16(const float* __restrict__ X, f16* __restrict__ Xh,
                          f16* __restrict__ Xl, int n)
{
  int i = (blockIdx.x*256 + threadIdx.x)*4;
  if (i >= n) return;
  float4 v = *(const float4*)(X+i);
  f16x4 h, l;
  h[0]=(_Float16)v.x; h[1]=(_Float16)v.y; h[2]=(_Float16)v.z; h[3]=(_Float16)v.w;
  l[0]=(_Float16)(v.x-(float)h[0]); l[1]=(_Float16)(v.y-(float)h[1]);
  l[2]=(_Float16)(v.z-(float)h[2]); l[3]=(_Float16)(v.w-(float)h[3]);
  *(f16x4*)(Xh+i)=h; *(f16x4*)(Xl+i)=l;
}

__global__ void build_bt_mhh(const float* __restrict__ M, f16* __restrict__ Bh, f16* __restrict__ Bl)
{
  int idx = blockIdx.x*256 + threadIdx.x;   // 65536: BT[n][k] = M_hh[k][n]
  int n = idx >> 8, k = idx & 255;
  float v = M[(size_t)k*1024 + n];
  _Float16 h = (_Float16)v;
  Bh[idx] = h; Bl[idx] = (_Float16)(v - (float)h);
}

__global__ void build_bt_wcat(const float* __restrict__ M, f16* __restrict__ Bh, f16* __restrict__ Bl)
{
  int idx = blockIdx.x*256 + threadIdx.x;   // 196608: BT[j][k] = Wcat[k][j]
  int j = idx >> 8, k = idx & 255;
  float v;
  if (j < 256)      v = M[(size_t)j*1024 + 256 + k];            // a1 = M_hr^T
  else if (j < 512) v = M[(size_t)(256+k)*1024 + (j-256)];      // a2 = M_rh
  else              v = M[(size_t)(256 + j-512)*1024 + 256 + k];// a3 = M_rr^T
  _Float16 h = (_Float16)v;
  Bh[idx] = h; Bl[idx] = (_Float16)(v - (float)h);
}

// ------- M = Wq^T @ Wk (1024x1024), fp64 accumulate, split-K x8 -------------
// Bit-identical summation order to round-0/round-3 (slab ascending, jj
// ascending, same FMA sequence, z=8, reduce_m z-ascending).
// This round: conflict-free grouped LDS layout. Column c -> LDS offset
// (c>>2)*6 + (c&3) doubles (4-double groups at stride 6 = 48 B, so all
// double2 accesses stay 16 B aligned); row stride 98 doubles. Per-wave read
// bank starts (t*12)%32 = 8 distinct / 2-way each -> free (vs r3's
// As[16][66] pattern = 4-way on every b128 read, 1.05e7 conflicts).
__global__ __launch_bounds__(256) void gemm_tn_split(const float* __restrict__ A,
                                                     const float* __restrict__ B,
                                                     double* __restrict__ Cpart)
{
  __shared__ __align__(16) double As[16*98];
  __shared__ __align__(16) double Bs[16*98];
  const int tid = threadIdx.x;
  const int rb = blockIdx.x * 64, cb = blockIdx.y * 64;
  const int z  = blockIdx.z;
  const int ty = tid >> 4, tx = tid & 15;       // compute: 16x16 grid, 4x4 each
  const int aj = tid >> 4, ag = tid & 15;       // staging: row aj, 4-col group ag
  double acc[4][4] = {};
  const int jbeg = z * 128;

  const float* gA = A + (size_t)(jbeg+aj)*1024 + rb + ag*4;
  const float* gB = B + (size_t)(jbeg+aj)*1024 + cb + ag*4;
  float4 av = *(const float4*)gA;
  float4 bv = *(const float4*)gB;

  const int wbase = aj*98 + ag*6;
  const int aoff  = ty*6, boff = tx*6;

  for (int t0 = 0; t0 < 8; ++t0) {
    __syncthreads();
    {
      double2* wa = (double2*)(As + wbase);
      double2* wb = (double2*)(Bs + wbase);
      wa[0] = make_double2((double)av.x, (double)av.y);
      wa[1] = make_double2((double)av.z, (double)av.w);
      wb[0] = make_double2((double)bv.x, (double)bv.y);
      wb[1] = make_double2((double)bv.z, (double)bv.w);
    }
    __syncthreads();
    if (t0 < 7){
      gA += 16*1024; gB += 16*1024;
      av = *(const float4*)gA;
      bv = *(const float4*)gB;
    }
#pragma unroll
    for (int jj=0; jj<16; ++jj){
      const double* pa = As + jj*98 + aoff;
      const double* pb = Bs + jj*98 + boff;
      double2 a01 = *(const double2*)(pa);
      double2 a23 = *(const double2*)(pa+2);
      double2 b01 = *(const double2*)(pb);
      double2 b23 = *(const double2*)(pb+2);
      double a0=a01.x, a1=a01.y, a2=a23.x, a3=a23.y;
      double b0=b01.x, b1=b01.y, b2=b23.x, b3=b23.y;
      acc[0][0]+=a0*b0; acc[0][1]+=a0*b1; acc[0][2]+=a0*b2; acc[0][3]+=a0*b3;
      acc[1][0]+=a1*b0; acc[1][1]+=a1*b1; acc[1][2]+=a1*b2; acc[1][3]+=a1*b3;
      acc[2][0]+=a2*b0; acc[2][1]+=a2*b1; acc[2][2]+=a2*b2; acc[2][3]+=a2*b3;
      acc[3][0]+=a3*b0; acc[3][1]+=a3*b1; acc[3][2]+=a3*b2; acc[3][3]+=a3*b3;
    }
  }
  double* Cz = Cpart + (size_t)z * 1048576;
#pragma unroll
  for (int i=0;i<4;++i)
#pragma unroll
    for (int j=0;j<4;++j)
      Cz[(size_t)(rb+ty*4+i)*1024 + cb+tx*4+j] = acc[i][j];
}

__global__ void reduce_m(const double* __restrict__ P, float* __restrict__ Mout)
{
  int i = blockIdx.x*256 + threadIdx.x;
  double s = 0.0;
#pragma unroll
  for (int z=0;z<8;++z) s += P[(size_t)i + (size_t)z*1048576];
  Mout[i] = (float)s;
}

// ---------------- query tables as GEMM --------------------------------------
__global__ void build_g(const float* __restrict__ qst, const float* __restrict__ qr,
                        float* __restrict__ G)
{
  int idx = blockIdx.x*256 + threadIdx.x;   // 65536
  int q = idx >> 9, k = idx & 511;
  G[idx] = (k < 256) ? qst[(size_t)q*256 + k] : qr[(size_t)q*256 + k - 256];
}

// Bq (512 x 1280): cols [qt1-proj | qt2-proj | qw-proj | M_gg]
__global__ void build_bq(const float* __restrict__ M, float* __restrict__ Bq)
{
  int idx = blockIdx.x*256 + threadIdx.x;   // 655360
  int k = idx / 1280, t = idx - k*1280;
  float v;
  if (t < 256)      v = M[(size_t)t*1024 + 512 + k];
  else if (t < 512) v = M[(size_t)(512+k)*1024 + (t-256)];
  else if (t < 768) v = M[(size_t)(256+(t-512))*1024 + 512 + k]
                      + M[(size_t)(512+k)*1024 + 256 + (t-512)];
  else              v = M[(size_t)(512+k)*1024 + 512 + (t-768)];
  Bq[idx] = v;
}

// fp32 GEMM 64x64 tile, conflict-aware, prefetch (for the tiny qtab product)
__global__ __launch_bounds__(256) void gemm64(const float* __restrict__ A, int lda,
                                              const float* __restrict__ B, int ldb,
                                              float* __restrict__ C, int ldc,
                                              int Mrows, int Kdim)
{
  __shared__ float As[16][68];
  __shared__ float Bs[16][68];
  const int tid = threadIdx.x;
  const int rb = blockIdx.x*64, cb = blockIdx.y*64;
  const int tx = tid & 15, ty = tid >> 4;
  const int a_r = tid >> 2, a_k = (tid & 3)*4;
  const int b_c = tid & 63, b_r0 = (tid >> 6)*4;
  const bool aok = (rb + a_r) < Mrows;
  float4 pa = make_float4(0.f,0.f,0.f,0.f);
  float pb[4];
  if (aok) pa = *(const float4*)(A + (size_t)(rb+a_r)*lda + a_k);
#pragma unroll
  for (int j=0;j<4;++j) pb[j] = B[(size_t)(b_r0+j)*ldb + cb + b_c];
  float acc[4][4] = {};
  const int NK = Kdim >> 4;
  for (int t0=0; t0<NK; ++t0){
    __syncthreads();
    As[a_k+0][a_r]=pa.x; As[a_k+1][a_r]=pa.y; As[a_k+2][a_r]=pa.z; As[a_k+3][a_r]=pa.w;
#pragma unroll
    for (int j=0;j<4;++j) Bs[b_r0+j][b_c] = pb[j];
    __syncthreads();
    if (t0+1 < NK){
      int k0 = (t0+1) << 4;
      if (aok) pa = *(const float4*)(A + (size_t)(rb+a_r)*lda + k0 + a_k);
#pragma unroll
      for (int j=0;j<4;++j) pb[j] = B[(size_t)(k0+b_r0+j)*ldb + cb + b_c];
    }
#pragma unroll
    for (int kk=0;kk<16;++kk){
      float a[4], b[4];
      *(float4*)&a[0] = *(const float4*)&As[kk][ty*4];
#pragma unroll
      for (int j=0;j<4;++j) b[j] = Bs[kk][tx + 16*j];
#pragma unroll
      for (int i=0;i<4;++i)
#pragma unroll
        for (int j=0;j<4;++j) acc[i][j] += a[i]*b[j];
    }
  }
#pragma unroll
  for (int i=0;i<4;++i){
    int r = rb + ty*4 + i;
    if (r < Mrows)
#pragma unroll
      for (int j=0;j<4;++j)
        C[(size_t)r*ldc + cb + tx + 16*j] = acc[i][j];
  }
}

__global__ __launch_bounds__(256) void qc_dot(const float* __restrict__ Ccat,
    const float* __restrict__ qst, const float* __restrict__ qr, float* __restrict__ qc)
{
  __shared__ float red[256];
  int q = blockIdx.x, t = threadIdx.x;
  float a = Ccat[(size_t)q*1280 + 768 + t]  * qst[(size_t)q*256 + t]
          + Ccat[(size_t)q*1280 + 1024 + t] * qr [(size_t)q*256 + t];
  red[t] = a;
  __syncthreads();
  for (int s=128; s>0; s>>=1){
    if (t < s) red[t] += red[t+s];
    __syncthreads();
  }
  if (t==0) qc[q] = red[0];
}

// ---------------- slim per-edge logits (non-g terms) ------------------------
__global__ __launch_bounds__(256) void slim_logits(const int* __restrict__ edges,
    const float* __restrict__ H, const float* __restrict__ U,
    const float* __restrict__ Rel,
    const float* __restrict__ Ct, const float* __restrict__ qc,
    float* __restrict__ logits)
{
  int lane = threadIdx.x & 63;
  int e = blockIdx.x*4 + (threadIdx.x >> 6);
  int q   = edges[(size_t)e*8 + 0];
  int src = edges[(size_t)e*8 + 6];
  int dst = edges[(size_t)e*8 + 7];
  const float4* hs = (const float4*)(H   + (size_t)src*256);
  const float4* hd = (const float4*)(H   + (size_t)dst*256);
  const float4* us = (const float4*)(U   + (size_t)src*256);
  const float4* rl = (const float4*)(Rel + (size_t)e*256);
  const float4* t1 = (const float4*)(Ct + (size_t)q*1280);
  const float4* t2 = (const float4*)(Ct + (size_t)q*1280 + 256);
  const float4* w4 = (const float4*)(Ct + (size_t)q*1280 + 512);
  float4 a, b, c;
  float s = 0.f;
  a = hd[lane]; b = us[lane]; c = t2[lane];
  s += a.x*(b.x+c.x) + a.y*(b.y+c.y) + a.z*(b.z+c.z) + a.w*(b.w+c.w);
  a = hs[lane]; c = t1[lane];
  s += a.x*c.x + a.y*c.y + a.z*c.z + a.w*c.w;
  a = rl[lane]; c = w4[lane];
  s += a.x*c.x + a.y*c.y + a.z*c.z + a.w*c.w;
#pragma unroll
  for (int off=32; off>0; off>>=1) s += __shfl_down(s, off);
  if (lane==0) logits[e] = s + qc[q];
}

// ---------------- segmented softmax over src-node segments ------------------
__global__ void segmax_k(const int* __restrict__ edges, const float* __restrict__ logits,
                         unsigned* __restrict__ menc, int nE)
{
  int e = blockIdx.x*256 + threadIdx.x; if (e >= nE) return;
  atomicMax(menc + edges[(size_t)e*8+6], fenc(logits[e]));
}
__global__ void segexp_k(const int* __restrict__ edges, const float* __restrict__ logits,
                         const unsigned* __restrict__ menc, float* __restrict__ ebuf,
                         float* __restrict__ ssum, int nE)
{
  int e = blockIdx.x*256 + threadIdx.x; if (e >= nE) return;
  int s = edges[(size_t)e*8+6];
  float ex = expf(logits[e] - fdec(menc[s]));
  ebuf[e] = ex;
  atomicAdd(ssum + s, ex);
}
template<int TGT>
__global__ void segsoft_k(const int* __restrict__ edges, const float* __restrict__ ebuf,
                          const float* __restrict__ ssum, float* __restrict__ soft,
                          const float* __restrict__ score, float* __restrict__ target, int nE)
{
  int e = blockIdx.x*256 + threadIdx.x; if (e >= nE) return;
  int s = edges[(size_t)e*8+6];
  float so = ebuf[e] / ssum[s];
  soft[e] = so;
  if (TGT) target[e] = so * score[s];
}

// ---------------- per-query top-64 (bitonic, matches top_k tie order) -------
__global__ __launch_bounds__(256) void topk_k(const float* __restrict__ target,
    const float* __restrict__ soft, const int* __restrict__ edges1,
    float* __restrict__ out0, float* __restrict__ out2, float* __restrict__ out3,
    int* __restrict__ p_src, int* __restrict__ p_dst, float* __restrict__ p_w)
{
  int qb = blockIdx.x, t = threadIdx.x;
  __shared__ float v[256];
  __shared__ int   ix[256];
  v[t] = target[(size_t)qb*256 + t];
  ix[t] = t;
  __syncthreads();
  for (int k=2; k<=256; k<<=1){
    for (int j=k>>1; j>0; j>>=1){
      int ixj = t ^ j;
      if (ixj > t){
        float va=v[t], vb=v[ixj]; int ia=ix[t], ib=ix[ixj];
        bool dir  = ((t & k) == 0);
        bool l_ab = (va > vb) || (va == vb && ia < ib);
        bool sw   = dir ? (!l_ab) : l_ab;
        if (sw){ v[t]=vb; v[ixj]=va; ix[t]=ib; ix[ixj]=ia; }
      }
      __syncthreads();
    }
  }
  if (t < 64){
    int oi = qb*256 + ix[t];
    int o  = qb*64 + t;
    out3[o] = (float)oi;
#pragma unroll
    for (int c2=0;c2<8;++c2) out2[(size_t)o*8 + c2] = (float)edges1[(size_t)oi*8 + c2];
    int s_ = edges1[(size_t)oi*8+6], d_ = edges1[(size_t)oi*8+7];
    p_src[o] = s_; p_dst[o] = d_; p_w[o] = soft[oi];
    atomicAdd(out0 + d_, v[t]);
  }
}

// ---------------- bucketized repr update ------------------------------------
__global__ void bucket_fill(const int* __restrict__ srcarr, int stride, int n,
                            int* __restrict__ counts, int* __restrict__ bucket,
                            int* __restrict__ over, int* __restrict__ n_over)
{
  int e = blockIdx.x*256 + threadIdx.x; if (e >= n) return;
  int s = srcarr[(size_t)e*stride];
  int pos = atomicAdd(counts + s, 1);
  if (pos < BCAP) bucket[(size_t)s*BCAP + pos] = e;
  else { int oi = atomicAdd(n_over, 1); over[oi] = e; }
}

__global__ __launch_bounds__(256) void fused_update(const int* __restrict__ counts,
    const int* __restrict__ bucket, const int* __restrict__ dstarr, int dstride,
    const float* __restrict__ w, const float* __restrict__ Hin, float* __restrict__ Hout)
{
  int lane = threadIdx.x & 63;
  int n = blockIdx.x*4 + (threadIdx.x >> 6);
  if (n >= NN) return;
  int cnt = counts[n];
  float fac = cnt > 0 ? 0.2f : 1.0f;
  float4 h = ((const float4*)(Hin + (size_t)n*256))[lane];
  float4 acc = make_float4(fac*h.x, fac*h.y, fac*h.z, fac*h.w);
  int m = cnt < BCAP ? cnt : BCAP;
  for (int i=0;i<m;++i){
    int e = bucket[(size_t)n*BCAP + i];
    int d = dstarr[(size_t)e*dstride];
    float f = 0.8f * w[e];
    float4 vv = ((const float4*)(Hin + (size_t)d*256))[lane];
    acc.x += f*vv.x; acc.y += f*vv.y; acc.z += f*vv.z; acc.w += f*vv.w;
  }
  ((float4*)(Hout + (size_t)n*256))[lane] = acc;
}

__global__ __launch_bounds__(256) void over_k(const int* __restrict__ over,
    const int* __restrict__ n_over,
    const int* __restrict__ srcarr, int sstride,
    const int* __restrict__ dstarr, int dstride,
    const float* __restrict__ w, const float* __restrict__ Hin, float* __restrict__ Hout)
{
  int lane = threadIdx.x & 63;
  int i = blockIdx.x*4 + (threadIdx.x >> 6);
  if (i >= *n_over) return;
  int e = over[i];
  int s = srcarr[(size_t)e*sstride], d = dstarr[(size_t)e*dstride];
  float f = 0.8f * w[e];
  float4 vv = ((const float4*)(Hin + (size_t)d*256))[lane];
  float* o = Hout + (size_t)s*256 + lane*4;
  atomicAdd(o+0, f*vv.x); atomicAdd(o+1, f*vv.y);
  atomicAdd(o+2, f*vv.z); atomicAdd(o+3, f*vv.w);
}

// ---------------- host launch ------------------------------------------------
extern "C" void kernel_launch(void* const* d_in, const int* in_sizes, int n_in,
                              void* d_out, int out_size, void* d_ws, size_t ws_size,
                              hipStream_t stream)
{
  const float* score = (const float*)d_in[0];
  const float* H0    = (const float*)d_in[1];
  const int*   edges0= (const int*)d_in[2];
  const int*   edges1= (const int*)d_in[3];
  const float* rel0  = (const float*)d_in[4];
  const float* rel1  = (const float*)d_in[5];
  const float* qst   = (const float*)d_in[6];
  const float* qr    = (const float*)d_in[7];
  const float* Wq    = (const float*)d_in[8];
  const float* Wk    = (const float*)d_in[9];
  const float* Wl    = (const float*)d_in[10];
  const float* bl    = (const float*)d_in[11];
  (void)in_sizes; (void)n_in; (void)out_size; (void)ws_size;

  float* out0 = (float*)d_out;
  float* out1 = out0 + NN;
  float* out2 = out1 + (size_t)NN*D;
  float* out3 = out2 + (size_t)NQ*ME*8;

  float* ws     = (float*)d_ws;
  float* Mbuf   = ws;                          // 1,048,576
  float* Ccat   = ws + 1048576;                // 128x1280 = 163,840
  float* qcv    = ws + 1212416;                // 128
  float* G      = ws + 1212544;                // 65,536
  float* logits = ws + 1278080;                // 32,768
  float* ebuf   = ws + 1310848;
  float* soft   = ws + 1343616;
  float* target = ws + 1376384;
  unsigned* menc= (unsigned*)(ws + 1409152);   // 50,000
  float* ssum   = ws + 1459152;                // 50,000
  int* p_src    = (int*)(ws + 1509152);        // 8,192
  int* p_dst    = (int*)(ws + 1517344);
  float* p_w    = ws + 1525536;                // ends 1,533,728
  float* Bq     = ws + 1533728;                // 512x1280 = 655,360 -> 2,189,088
  float* U      = ws + 2189088;                // 12,800,000 -> 14,989,088
  float* Hnew   = ws + 14989088;               // 12,800,000 -> 27,789,088
  float* SCR    = ws + 27789088;
  int* counts = (int*)SCR;                     // 50,000
  int* n_over = (int*)(SCR + 50000);           // 1
  int* over   = (int*)(SCR + 50056);           // 32,768
  int* bucket = (int*)(SCR + 100000);          // 1,600,000 -> SCR+1,700,000
  float* P0   = SCR + 2000000;                 // = ws + 29,789,088
  double* Mpart = (double*)P0;                 // 8M doubles = 16M floats (dead after reduce_m)
  f16* mhh_h  = (f16*)P0;                      // aliases Mpart (built after reduce_m)
  f16* mhh_l  = (f16*)(P0 + 32768);
  f16* wcat_h = (f16*)(P0 + 65536);
  f16* wcat_l = (f16*)(P0 + 163840);
  f16* wl_h   = (f16*)(P0 + 262144);
  f16* wl_l   = (f16*)(P0 + 294912);           // ends P0+327,680 (~186 MB total ws)
  float* Hpre = U;                             // alias: U dead before Hpre written

  hipMemsetAsync(out0, 0, (size_t)NN*4, stream);
  hipMemsetAsync(menc, 0, (size_t)NN*4, stream);
  hipMemsetAsync(ssum, 0, (size_t)NN*4, stream);

  // setup: M (fp64 split-K x8), query tables via GEMM, f16 B builders
  gemm_tn_split<<<dim3(16,16,8), 256, 0, stream>>>(Wq, Wk, Mpart);
  reduce_m<<<4096, 256, 0, stream>>>(Mpart, Mbuf);
  build_g<<<256, 256, 0, stream>>>(qst, qr, G);
  build_bq<<<2560, 256, 0, stream>>>(Mbuf, Bq);
  gemm64<<<dim3(2,20), 256, 0, stream>>>(G, 512, Bq, 1280, Ccat, 1280, NQ, 512);
  qc_dot<<<NQ, 256, 0, stream>>>(Ccat, qst, qr, qcv);
  build_bt_mhh<<<256, 256, 0, stream>>>(Mbuf, mhh_h, mhh_l);
  build_bt_wcat<<<768, 256, 0, stream>>>(Mbuf, wcat_h, wcat_l);
  split_f16<<<64, 256, 0, stream>>>(Wl, wl_h, wl_l, 65536);   // BT_wl == Wl

  // ---- call 1: edges1 / rel1 / H0 ----
  hgemm<0><<<dim3(391,2), 256, 0, stream>>>(H0, NN, mhh_h, mhh_l, U, 256, nullptr);
  slim_logits<<<NE/4, 256, 0, stream>>>(edges1, H0, U, rel1, Ccat, qcv, logits);
  hgemm_rel<<<dim3(256,6), 256, 0, stream>>>(rel1, wcat_h, wcat_l, edges1, H0, rel1, logits);

  segmax_k<<<NE/256, 256, 0, stream>>>(edges1, logits, menc, NE);
  segexp_k<<<NE/256, 256, 0, stream>>>(edges1, logits, menc, ebuf, ssum, NE);
  segsoft_k<1><<<NE/256, 256, 0, stream>>>(edges1, ebuf, ssum, soft, score, target, NE);

  topk_k<<<NQ, 256, 0, stream>>>(target, soft, edges1, out0, out2, out3, p_src, p_dst, p_w);

  hipMemsetAsync(counts, 0, (size_t)NN*4, stream);
  hipMemsetAsync(n_over, 0, 4, stream);
  bucket_fill<<<(NQ*ME+255)/256, 256, 0, stream>>>(p_src, 1, NQ*ME, counts, bucket, over, n_over);
  fused_update<<<(NN+3)/4, 256, 0, stream>>>(counts, bucket, p_dst, 1, p_w, H0, Hnew);
  over_k<<<(NQ*ME)/4, 256, 0, stream>>>(over, n_over, p_src, 1, p_dst, 1, p_w, H0, Hnew);

  hipMemsetAsync(menc, 0, (size_t)NN*4, stream);
  hipMemsetAsync(ssum, 0, (size_t)NN*4, stream);

  // ---- call 2: edges0 / rel0 / Hnew ----
  hgemm<0><<<dim3(391,2), 256, 0, stream>>>(Hnew, NN, mhh_h, mhh_l, U, 256, nullptr);
  slim_logits<<<NE/4, 256, 0, stream>>>(edges0, Hnew, U, rel0, Ccat, qcv, logits);
  hgemm_rel<<<dim3(256,6), 256, 0, stream>>>(rel0, wcat_h, wcat_l, edges0, Hnew, rel0, logits);

  segmax_k<<<NE/256, 256, 0, stream>>>(edges0, logits, menc, NE);
  segexp_k<<<NE/256, 256, 0, stream>>>(edges0, logits, menc, ebuf, ssum, NE);
  segsoft_k<0><<<NE/256, 256, 0, stream>>>(edges0, ebuf, ssum, soft, nullptr, nullptr, NE);

  hipMemsetAsync(counts, 0, (size_t)NN*4, stream);
  hipMemsetAsync(n_over, 0, 4, stream);
  bucket_fill<<<NE/256, 256, 0, stream>>>(edges0 + 6, 8, NE, counts, bucket, over, n_over);
  fused_update<<<(NN+3)/4, 256, 0, stream>>>(counts, bucket, edges0 + 7, 8, soft, Hnew, Hpre);
  over_k<<<NE/4, 256, 0, stream>>>(over, n_over, edges0 + 6, 8, edges0 + 7, 8, soft, Hnew, Hpre);

  // final: out1 = leaky_relu(Hpre @ Wl^T + bl)
  hgemm<1><<<dim3(391,2), 256, 0, stream>>>(Hpre, NN, wl_h, wl_l, out1, 256, bl);
}

// Round 7
// 600.382 us; speedup vs baseline: 1.0826x; 1.0308x over previous
//
#include <hip/hip_runtime.h>

#define NN 50000
#define D 256
#define NQ 128
#define PG 256
#define NE 32768
#define ME 64
#define BCAP 32
#define KDIM 256
#define NKT 8

typedef _Float16 f16;
typedef __attribute__((ext_vector_type(4))) _Float16 f16x4;
typedef __attribute__((ext_vector_type(8))) _Float16 f16x8;
typedef __attribute__((ext_vector_type(4))) float f32x4;

#define MFMA16(a,b,c) __builtin_amdgcn_mfma_f32_16x16x32_f16(a,b,c,0,0,0)

__device__ __forceinline__ unsigned fenc(float f){
  unsigned b = __float_as_uint(f);
  return (b & 0x80000000u) ? ~b : (b | 0x80000000u);
}
__device__ __forceinline__ float fdec(unsigned u){
  unsigned b = (u & 0x80000000u) ? (u & 0x7fffffffu) : ~u;
  return __uint_as_float(b);
}
__device__ __forceinline__ void split8(float4 a, float4 b, f16x8& h, f16x8& l){
  float v[8] = {a.x,a.y,a.z,a.w,b.x,b.y,b.z,b.w};
#pragma unroll
  for (int i=0;i<8;++i){
    _Float16 hh = (_Float16)v[i];
    h[i] = hh;
    l[i] = (_Float16)(v[i] - (float)hh);
  }
}

// ---------- fp16x3 MFMA GEMM: C(f32) = A_f32(M x 256) @ (Bh+Bl)^T -----------
// v2: one block covers 128 rows x FULL 256 cols (8 waves, 512 thr) so the A
// tile is staged once per row-block (was twice). Per-element MFMA sequence
// identical to v1 -> bit-identical C.
template<int EPI>
__global__ __launch_bounds__(512) void hgemm(const float* __restrict__ A,
                                             int Mrows,
                                             const f16* __restrict__ Bh, const f16* __restrict__ Bl,
                                             float* __restrict__ C, int ldc,
                                             const float* __restrict__ bias)
{
  __shared__ f16 AsH[128*40], AsL[128*40], BsH[256*40], BsL[256*40];
  const int tid = threadIdx.x;
  const int rb = blockIdx.x*128;
  const int arow = tid >> 2, ako = (tid & 3)*8;
  const int brow = tid >> 1, bko = (tid & 1)*16;
  const bool aok = (rb + arow) < Mrows;
  const int lane = tid & 63, wv = tid >> 6;
  const int qrw = (wv & 1)*64, qcw = (wv >> 1)*64;
  const int lm = lane & 15, qd = lane >> 4;

  const float* gA = A + (size_t)(rb+arow)*KDIM + ako;
  const f16* gBh = Bh + (size_t)brow*KDIM + bko;
  const f16* gBl = Bl + (size_t)brow*KDIM + bko;

  float4 pa0=make_float4(0.f,0.f,0.f,0.f), pa1=pa0;
  f16x8 pbh0, pbh1, pbl0, pbl1;
  if (aok){ pa0 = *(const float4*)gA; pa1 = *(const float4*)(gA+4); }
  pbh0 = *(const f16x8*)gBh; pbh1 = *(const f16x8*)(gBh+8);
  pbl0 = *(const f16x8*)gBl; pbl1 = *(const f16x8*)(gBl+8);

  f32x4 acc[4][4];
#pragma unroll
  for (int t=0;t<4;++t)
#pragma unroll
    for (int u=0;u<4;++u)
#pragma unroll
      for (int r=0;r<4;++r) acc[t][u][r] = 0.f;

  const int wabase = arow*40 + ako;
  const int wbbase = brow*40 + bko;
  for (int kt = 0; kt < NKT; ++kt){
    __syncthreads();
    {
      f16x8 h0,l0;
      split8(pa0,pa1,h0,l0);
      *(f16x8*)(AsH + wabase) = h0;
      *(f16x8*)(AsL + wabase) = l0;
      *(f16x8*)(BsH + wbbase) = pbh0; *(f16x8*)(BsH + wbbase + 8) = pbh1;
      *(f16x8*)(BsL + wbbase) = pbl0; *(f16x8*)(BsL + wbbase + 8) = pbl1;
    }
    __syncthreads();
    if (kt+1 < NKT){
      const int k0 = (kt+1)*32;
      if (aok){ pa0 = *(const float4*)(gA + k0); pa1 = *(const float4*)(gA + k0 + 4); }
      pbh0 = *(const f16x8*)(gBh + k0); pbh1 = *(const f16x8*)(gBh + k0 + 8);
      pbl0 = *(const f16x8*)(gBl + k0); pbl1 = *(const f16x8*)(gBl + k0 + 8);
    }
    f16x8 fah[4], fal[4], fbh[4], fbl[4];
#pragma unroll
    for (int t=0;t<4;++t){
      int off = (qrw + t*16 + lm)*40 + qd*8;
      fah[t] = *(const f16x8*)(AsH + off);
      fal[t] = *(const f16x8*)(AsL + off);
    }
#pragma unroll
    for (int u=0;u<4;++u){
      int off = (qcw + u*16 + lm)*40 + qd*8;
      fbh[u] = *(const f16x8*)(BsH + off);
      fbl[u] = *(const f16x8*)(BsL + off);
    }
#pragma unroll
    for (int t=0;t<4;++t)
#pragma unroll
      for (int u=0;u<4;++u){
        acc[t][u] = MFMA16(fah[t], fbh[u], acc[t][u]);
        acc[t][u] = MFMA16(fah[t], fbl[u], acc[t][u]);
        acc[t][u] = MFMA16(fal[t], fbh[u], acc[t][u]);
      }
  }
#pragma unroll
  for (int t=0;t<4;++t){
#pragma unroll
    for (int u=0;u<4;++u){
      int col = qcw + u*16 + lm;
      f32x4 v = acc[t][u];
#pragma unroll
      for (int r=0;r<4;++r){
        int rg = rb + qrw + t*16 + qd*4 + r;
        if (rg < Mrows){
          float x = v[r];
          if (EPI==1){ x += bias[col]; x = x > 0.f ? x : 0.01f*x; }
          C[(size_t)rg*ldc + col] = x;
        }
      }
    }
  }
}

// ---- rel GEMM with fused logits epilogue: partial = sum_j C[e][j]*X[e][j] ---
// v2: grid (256, 3) — one block per (row-tile, section), full 256-col section
// per block (8 waves, 512 thr). A (rel) staged 3x instead of 6x. Each
// atomicAdd contributes the identical f32 partial as v1 (same 4-col dot, same
// order); only block packaging changed. sec 0 -> X=H[src]; 1 -> H[dst];
// 2 -> rel[e].
__global__ __launch_bounds__(512) void hgemm_rel(const float* __restrict__ A,
                                                 const f16* __restrict__ Bh, const f16* __restrict__ Bl,
                                                 const int* __restrict__ edges,
                                                 const float* __restrict__ H,
                                                 const float* __restrict__ Rel,
                                                 float* __restrict__ logits)
{
  __shared__ f16 AsH[128*40], AsL[128*40], BsH[256*40], BsL[256*40];
  __shared__ int sIdx[128];
  const int tid = threadIdx.x;
  const int rb = blockIdx.x*128;
  const int sec = blockIdx.y;
  const int cb = sec*256;
  const int arow = tid >> 2, ako = (tid & 3)*8;
  const int brow = tid >> 1, bko = (tid & 1)*16;
  const int lane = tid & 63, wv = tid >> 6;
  const int qrw = (wv & 1)*64, qcw = (wv >> 1)*64;
  const int lm = lane & 15, qd = lane >> 4;

  if (tid < 128){
    int e = rb + tid;
    sIdx[tid] = (sec==0) ? edges[(size_t)e*8+6] : (sec==1 ? edges[(size_t)e*8+7] : 0);
  }

  const float* gA = A + (size_t)(rb+arow)*KDIM + ako;
  const f16* gBh = Bh + (size_t)(cb+brow)*KDIM + bko;
  const f16* gBl = Bl + (size_t)(cb+brow)*KDIM + bko;

  float4 pa0 = *(const float4*)gA, pa1 = *(const float4*)(gA+4);
  f16x8 pbh0 = *(const f16x8*)gBh, pbh1 = *(const f16x8*)(gBh+8);
  f16x8 pbl0 = *(const f16x8*)gBl, pbl1 = *(const f16x8*)(gBl+8);

  f32x4 acc[4][4];
#pragma unroll
  for (int t=0;t<4;++t)
#pragma unroll
    for (int u=0;u<4;++u)
#pragma unroll
      for (int r=0;r<4;++r) acc[t][u][r] = 0.f;

  const int wabase = arow*40 + ako;
  const int wbbase = brow*40 + bko;
  for (int kt = 0; kt < NKT; ++kt){
    __syncthreads();
    {
      f16x8 h0,l0;
      split8(pa0,pa1,h0,l0);
      *(f16x8*)(AsH + wabase) = h0;
      *(f16x8*)(AsL + wabase) = l0;
      *(f16x8*)(BsH + wbbase) = pbh0; *(f16x8*)(BsH + wbbase + 8) = pbh1;
      *(f16x8*)(BsL + wbbase) = pbl0; *(f16x8*)(BsL + wbbase + 8) = pbl1;
    }
    __syncthreads();
    if (kt+1 < NKT){
      const int k0 = (kt+1)*32;
      pa0 = *(const float4*)(gA + k0); pa1 = *(const float4*)(gA + k0 + 4);
      pbh0 = *(const f16x8*)(gBh + k0); pbh1 = *(const f16x8*)(gBh + k0 + 8);
      pbl0 = *(const f16x8*)(gBl + k0); pbl1 = *(const f16x8*)(gBl + k0 + 8);
    }
    f16x8 fah[4], fal[4], fbh[4], fbl[4];
#pragma unroll
    for (int t=0;t<4;++t){
      int off = (qrw + t*16 + lm)*40 + qd*8;
      fah[t] = *(const f16x8*)(AsH + off);
      fal[t] = *(const f16x8*)(AsL + off);
    }
#pragma unroll
    for (int u=0;u<4;++u){
      int off = (qcw + u*16 + lm)*40 + qd*8;
      fbh[u] = *(const f16x8*)(BsH + off);
      fbl[u] = *(const f16x8*)(BsL + off);
    }
#pragma unroll
    for (int t=0;t<4;++t)
#pragma unroll
      for (int u=0;u<4;++u){
        acc[t][u] = MFMA16(fah[t], fbh[u], acc[t][u]);
        acc[t][u] = MFMA16(fah[t], fbl[u], acc[t][u]);
        acc[t][u] = MFMA16(fal[t], fbh[u], acc[t][u]);
      }
  }
  const int cbase = qcw + lm;
#pragma unroll
  for (int t=0;t<4;++t){
#pragma unroll
    for (int r=0;r<4;++r){
      int lrow = qrw + t*16 + qd*4 + r;
      int e = rb + lrow;
      const float* xb = (sec==2) ? (Rel + (size_t)e*256)
                                 : (H + (size_t)sIdx[lrow]*256);
      float p = acc[t][0][r]*xb[cbase]
              + acc[t][1][r]*xb[cbase+16]
              + acc[t][2][r]*xb[cbase+32]
              + acc[t][3][r]*xb[cbase+48];
      p += __shfl_xor(p, 1); p += __shfl_xor(p, 2);
      p += __shfl_xor(p, 4); p += __shfl_xor(p, 8);
      if (lm == 0) atomicAdd(logits + e, p);
    }
  }
}

// ---------------- fp16 split helper (small matrices only) -------------------
__global__ void split_f16(const float* __restrict__ X, f16* __restrict__ Xh,
                          f16* __restrict__ Xl, int n)
{
  int i = (blockIdx.x*256 + threadIdx.x)*4;
  if (i >= n) return;
  float4 v = *(const float4*)(X+i);
  f16x4 h, l;
  h[0]=(_Float16)v.x; h[1]=(_Float16)v.y; h[2]=(_Float16)v.z; h[3]=(_Float16)v.w;
  l[0]=(_Float16)(v.x-(float)h[0]); l[1]=(_Float16)(v.y-(float)h[1]);
  l[2]=(_Float16)(v.z-(float)h[2]); l[3]=(_Float16)(v.w-(float)h[3]);
  *(f16x4*)(Xh+i)=h; *(f16x4*)(Xl+i)=l;
}

__global__ void build_bt_mhh(const float* __restrict__ M, f16* __restrict__ Bh, f16* __restrict__ Bl)
{
  int idx = blockIdx.x*256 + threadIdx.x;   // 65536: BT[n][k] = M_hh[k][n]
  int n = idx >> 8, k = idx & 255;
  float v = M[(size_t)k*1024 + n];
  _Float16 h = (_Float16)v;
  Bh[idx] = h; Bl[idx] = (_Float16)(v - (float)h);
}

__global__ void build_bt_wcat(const float* __restrict__ M, f16* __restrict__ Bh, f16* __restrict__ Bl)
{
  int idx = blockIdx.x*256 + threadIdx.x;   // 196608: BT[j][k] = Wcat[k][j]
  int j = idx >> 8, k = idx & 255;
  float v;
  if (j < 256)      v = M[(size_t)j*1024 + 256 + k];            // a1 = M_hr^T
  else if (j < 512) v = M[(size_t)(256+k)*1024 + (j-256)];      // a2 = M_rh
  else              v = M[(size_t)(256 + j-512)*1024 + 256 + k];// a3 = M_rr^T
  _Float16 h = (_Float16)v;
  Bh[idx] = h; Bl[idx] = (_Float16)(v - (float)h);
}

// ------- M = Wq^T @ Wk (1024x1024), fp64 accumulate, split-K x8 -------------
// Bit-identical summation order to round-0/round-3. Conflict-free grouped LDS
// layout (r6-validated): column c -> offset (c>>2)*6 + (c&3) doubles, row
// stride 98; per-wave read bank starts (t*12)%32 = 2-way max (free).
__global__ __launch_bounds__(256) void gemm_tn_split(const float* __restrict__ A,
                                                     const float* __restrict__ B,
                                                     double* __restrict__ Cpart)
{
  __shared__ __align__(16) double As[16*98];
  __shared__ __align__(16) double Bs[16*98];
  const int tid = threadIdx.x;
  const int rb = blockIdx.x * 64, cb = blockIdx.y * 64;
  const int z  = blockIdx.z;
  const int ty = tid >> 4, tx = tid & 15;       // compute: 16x16 grid, 4x4 each
  const int aj = tid >> 4, ag = tid & 15;       // staging: row aj, 4-col group ag
  double acc[4][4] = {};
  const int jbeg = z * 128;

  const float* gA = A + (size_t)(jbeg+aj)*1024 + rb + ag*4;
  const float* gB = B + (size_t)(jbeg+aj)*1024 + cb + ag*4;
  float4 av = *(const float4*)gA;
  float4 bv = *(const float4*)gB;

  const int wbase = aj*98 + ag*6;
  const int aoff  = ty*6, boff = tx*6;

  for (int t0 = 0; t0 < 8; ++t0) {
    __syncthreads();
    {
      double2* wa = (double2*)(As + wbase);
      double2* wb = (double2*)(Bs + wbase);
      wa[0] = make_double2((double)av.x, (double)av.y);
      wa[1] = make_double2((double)av.z, (double)av.w);
      wb[0] = make_double2((double)bv.x, (double)bv.y);
      wb[1] = make_double2((double)bv.z, (double)bv.w);
    }
    __syncthreads();
    if (t0 < 7){
      gA += 16*1024; gB += 16*1024;
      av = *(const float4*)gA;
      bv = *(const float4*)gB;
    }
#pragma unroll
    for (int jj=0; jj<16; ++jj){
      const double* pa = As + jj*98 + aoff;
      const double* pb = Bs + jj*98 + boff;
      double2 a01 = *(const double2*)(pa);
      double2 a23 = *(const double2*)(pa+2);
      double2 b01 = *(const double2*)(pb);
      double2 b23 = *(const double2*)(pb+2);
      double a0=a01.x, a1=a01.y, a2=a23.x, a3=a23.y;
      double b0=b01.x, b1=b01.y, b2=b23.x, b3=b23.y;
      acc[0][0]+=a0*b0; acc[0][1]+=a0*b1; acc[0][2]+=a0*b2; acc[0][3]+=a0*b3;
      acc[1][0]+=a1*b0; acc[1][1]+=a1*b1; acc[1][2]+=a1*b2; acc[1][3]+=a1*b3;
      acc[2][0]+=a2*b0; acc[2][1]+=a2*b1; acc[2][2]+=a2*b2; acc[2][3]+=a2*b3;
      acc[3][0]+=a3*b0; acc[3][1]+=a3*b1; acc[3][2]+=a3*b2; acc[3][3]+=a3*b3;
    }
  }
  double* Cz = Cpart + (size_t)z * 1048576;
#pragma unroll
  for (int i=0;i<4;++i)
#pragma unroll
    for (int j=0;j<4;++j)
      Cz[(size_t)(rb+ty*4+i)*1024 + cb+tx*4+j] = acc[i][j];
}

__global__ void reduce_m(const double* __restrict__ P, float* __restrict__ Mout)
{
  int i = blockIdx.x*256 + threadIdx.x;
  double s = 0.0;
#pragma unroll
  for (int z=0;z<8;++z) s += P[(size_t)i + (size_t)z*1048576];
  Mout[i] = (float)s;
}

// ---------------- query tables as GEMM --------------------------------------
__global__ void build_g(const float* __restrict__ qst, const float* __restrict__ qr,
                        float* __restrict__ G)
{
  int idx = blockIdx.x*256 + threadIdx.x;   // 65536
  int q = idx >> 9, k = idx & 511;
  G[idx] = (k < 256) ? qst[(size_t)q*256 + k] : qr[(size_t)q*256 + k - 256];
}

// Bq (512 x 1280): cols [qt1-proj | qt2-proj | qw-proj | M_gg]
__global__ void build_bq(const float* __restrict__ M, float* __restrict__ Bq)
{
  int idx = blockIdx.x*256 + threadIdx.x;   // 655360
  int k = idx / 1280, t = idx - k*1280;
  float v;
  if (t < 256)      v = M[(size_t)t*1024 + 512 + k];
  else if (t < 512) v = M[(size_t)(512+k)*1024 + (t-256)];
  else if (t < 768) v = M[(size_t)(256+(t-512))*1024 + 512 + k]
                      + M[(size_t)(512+k)*1024 + 256 + (t-512)];
  else              v = M[(size_t)(512+k)*1024 + 512 + (t-768)];
  Bq[idx] = v;
}

// fp32 GEMM 64x64 tile, conflict-aware, prefetch (for the tiny qtab product)
__global__ __launch_bounds__(256) void gemm64(const float* __restrict__ A, int lda,
                                              const float* __restrict__ B, int ldb,
                                              float* __restrict__ C, int ldc,
                                              int Mrows, int Kdim)
{
  __shared__ float As[16][68];
  __shared__ float Bs[16][68];
  const int tid = threadIdx.x;
  const int rb = blockIdx.x*64, cb = blockIdx.y*64;
  const int tx = tid & 15, ty = tid >> 4;
  const int a_r = tid >> 2, a_k = (tid & 3)*4;
  const int b_c = tid & 63, b_r0 = (tid >> 6)*4;
  const bool aok = (rb + a_r) < Mrows;
  float4 pa = make_float4(0.f,0.f,0.f,0.f);
  float pb[4];
  if (aok) pa = *(const float4*)(A + (size_t)(rb+a_r)*lda + a_k);
#pragma unroll
  for (int j=0;j<4;++j) pb[j] = B[(size_t)(b_r0+j)*ldb + cb + b_c];
  float acc[4][4] = {};
  const int NK = Kdim >> 4;
  for (int t0=0; t0<NK; ++t0){
    __syncthreads();
    As[a_k+0][a_r]=pa.x; As[a_k+1][a_r]=pa.y; As[a_k+2][a_r]=pa.z; As[a_k+3][a_r]=pa.w;
#pragma unroll
    for (int j=0;j<4;++j) Bs[b_r0+j][b_c] = pb[j];
    __syncthreads();
    if (t0+1 < NK){
      int k0 = (t0+1) << 4;
      if (aok) pa = *(const float4*)(A + (size_t)(rb+a_r)*lda + k0 + a_k);
#pragma unroll
      for (int j=0;j<4;++j) pb[j] = B[(size_t)(k0+b_r0+j)*ldb + cb + b_c];
    }
#pragma unroll
    for (int kk=0;kk<16;++kk){
      float a[4], b[4];
      *(float4*)&a[0] = *(const float4*)&As[kk][ty*4];
#pragma unroll
      for (int j=0;j<4;++j) b[j] = Bs[kk][tx + 16*j];
#pragma unroll
      for (int i=0;i<4;++i)
#pragma unroll
        for (int j=0;j<4;++j) acc[i][j] += a[i]*b[j];
    }
  }
#pragma unroll
  for (int i=0;i<4;++i){
    int r = rb + ty*4 + i;
    if (r < Mrows)
#pragma unroll
      for (int j=0;j<4;++j)
        C[(size_t)r*ldc + cb + tx + 16*j] = acc[i][j];
  }
}

__global__ __launch_bounds__(256) void qc_dot(const float* __restrict__ Ccat,
    const float* __restrict__ qst, const float* __restrict__ qr, float* __restrict__ qc)
{
  __shared__ float red[256];
  int q = blockIdx.x, t = threadIdx.x;
  float a = Ccat[(size_t)q*1280 + 768 + t]  * qst[(size_t)q*256 + t]
          + Ccat[(size_t)q*1280 + 1024 + t] * qr [(size_t)q*256 + t];
  red[t] = a;
  __syncthreads();
  for (int s=128; s>0; s>>=1){
    if (t < s) red[t] += red[t+s];
    __syncthreads();
  }
  if (t==0) qc[q] = red[0];
}

// ---------------- slim per-edge logits (non-g terms) ------------------------
__global__ __launch_bounds__(256) void slim_logits(const int* __restrict__ edges,
    const float* __restrict__ H, const float* __restrict__ U,
    const float* __restrict__ Rel,
    const float* __restrict__ Ct, const float* __restrict__ qc,
    float* __restrict__ logits)
{
  int lane = threadIdx.x & 63;
  int e = blockIdx.x*4 + (threadIdx.x >> 6);
  int q   = edges[(size_t)e*8 + 0];
  int src = edges[(size_t)e*8 + 6];
  int dst = edges[(size_t)e*8 + 7];
  const float4* hs = (const float4*)(H   + (size_t)src*256);
  const float4* hd = (const float4*)(H   + (size_t)dst*256);
  const float4* us = (const float4*)(U   + (size_t)src*256);
  const float4* rl = (const float4*)(Rel + (size_t)e*256);
  const float4* t1 = (const float4*)(Ct + (size_t)q*1280);
  const float4* t2 = (const float4*)(Ct + (size_t)q*1280 + 256);
  const float4* w4 = (const float4*)(Ct + (size_t)q*1280 + 512);
  float4 a, b, c;
  float s = 0.f;
  a = hd[lane]; b = us[lane]; c = t2[lane];
  s += a.x*(b.x+c.x) + a.y*(b.y+c.y) + a.z*(b.z+c.z) + a.w*(b.w+c.w);
  a = hs[lane]; c = t1[lane];
  s += a.x*c.x + a.y*c.y + a.z*c.z + a.w*c.w;
  a = rl[lane]; c = w4[lane];
  s += a.x*c.x + a.y*c.y + a.z*c.z + a.w*c.w;
#pragma unroll
  for (int off=32; off>0; off>>=1) s += __shfl_down(s, off);
  if (lane==0) logits[e] = s + qc[q];
}

// ---------------- segmented softmax over src-node segments ------------------
__global__ void segmax_k(const int* __restrict__ edges, const float* __restrict__ logits,
                         unsigned* __restrict__ menc, int nE)
{
  int e = blockIdx.x*256 + threadIdx.x; if (e >= nE) return;
  atomicMax(menc + edges[(size_t)e*8+6], fenc(logits[e]));
}
__global__ void segexp_k(const int* __restrict__ edges, const float* __restrict__ logits,
                         const unsigned* __restrict__ menc, float* __restrict__ ebuf,
                         float* __restrict__ ssum, int nE)
{
  int e = blockIdx.x*256 + threadIdx.x; if (e >= nE) return;
  int s = edges[(size_t)e*8+6];
  float ex = expf(logits[e] - fdec(menc[s]));
  ebuf[e] = ex;
  atomicAdd(ssum + s, ex);
}
template<int TGT>
__global__ void segsoft_k(const int* __restrict__ edges, const float* __restrict__ ebuf,
                          const float* __restrict__ ssum, float* __restrict__ soft,
                          const float* __restrict__ score, float* __restrict__ target, int nE)
{
  int e = blockIdx.x*256 + threadIdx.x; if (e >= nE) return;
  int s = edges[(size_t)e*8+6];
  float so = ebuf[e] / ssum[s];
  soft[e] = so;
  if (TGT) target[e] = so * score[s];
}

// ---------------- per-query top-64 (bitonic, matches top_k tie order) -------
__global__ __launch_bounds__(256) void topk_k(const float* __restrict__ target,
    const float* __restrict__ soft, const int* __restrict__ edges1,
    float* __restrict__ out0, float* __restrict__ out2, float* __restrict__ out3,
    int* __restrict__ p_src, int* __restrict__ p_dst, float* __restrict__ p_w)
{
  int qb = blockIdx.x, t = threadIdx.x;
  __shared__ float v[256];
  __shared__ int   ix[256];
  v[t] = target[(size_t)qb*256 + t];
  ix[t] = t;
  __syncthreads();
  for (int k=2; k<=256; k<<=1){
    for (int j=k>>1; j>0; j>>=1){
      int ixj = t ^ j;
      if (ixj > t){
        float va=v[t], vb=v[ixj]; int ia=ix[t], ib=ix[ixj];
        bool dir  = ((t & k) == 0);
        bool l_ab = (va > vb) || (va == vb && ia < ib);
        bool sw   = dir ? (!l_ab) : l_ab;
        if (sw){ v[t]=vb; v[ixj]=va; ix[t]=ib; ix[ixj]=ia; }
      }
      __syncthreads();
    }
  }
  if (t < 64){
    int oi = qb*256 + ix[t];
    int o  = qb*64 + t;
    out3[o] = (float)oi;
#pragma unroll
    for (int c2=0;c2<8;++c2) out2[(size_t)o*8 + c2] = (float)edges1[(size_t)oi*8 + c2];
    int s_ = edges1[(size_t)oi*8+6], d_ = edges1[(size_t)oi*8+7];
    p_src[o] = s_; p_dst[o] = d_; p_w[o] = soft[oi];
    atomicAdd(out0 + d_, v[t]);
  }
}

// ---------------- bucketized repr update ------------------------------------
__global__ void bucket_fill(const int* __restrict__ srcarr, int stride, int n,
                            int* __restrict__ counts, int* __restrict__ bucket,
                            int* __restrict__ over, int* __restrict__ n_over)
{
  int e = blockIdx.x*256 + threadIdx.x; if (e >= n) return;
  int s = srcarr[(size_t)e*stride];
  int pos = atomicAdd(counts + s, 1);
  if (pos < BCAP) bucket[(size_t)s*BCAP + pos] = e;
  else { int oi = atomicAdd(n_over, 1); over[oi] = e; }
}

__global__ __launch_bounds__(256) void fused_update(const int* __restrict__ counts,
    const int* __restrict__ bucket, const int* __restrict__ dstarr, int dstride,
    const float* __restrict__ w, const float* __restrict__ Hin, float* __restrict__ Hout)
{
  int lane = threadIdx.x & 63;
  int n = blockIdx.x*4 + (threadIdx.x >> 6);
  if (n >= NN) return;
  int cnt = counts[n];
  float fac = cnt > 0 ? 0.2f : 1.0f;
  float4 h = ((const float4*)(Hin + (size_t)n*256))[lane];
  float4 acc = make_float4(fac*h.x, fac*h.y, fac*h.z, fac*h.w);
  int m = cnt < BCAP ? cnt : BCAP;
  for (int i=0;i<m;++i){
    int e = bucket[(size_t)n*BCAP + i];
    int d = dstarr[(size_t)e*dstride];
    float f = 0.8f * w[e];
    float4 vv = ((const float4*)(Hin + (size_t)d*256))[lane];
    acc.x += f*vv.x; acc.y += f*vv.y; acc.z += f*vv.z; acc.w += f*vv.w;
  }
  ((float4*)(Hout + (size_t)n*256))[lane] = acc;
}

__global__ __launch_bounds__(256) void over_k(const int* __restrict__ over,
    const int* __restrict__ n_over,
    const int* __restrict__ srcarr, int sstride,
    const int* __restrict__ dstarr, int dstride,
    const float* __restrict__ w, const float* __restrict__ Hin, float* __restrict__ Hout)
{
  int lane = threadIdx.x & 63;
  int i = blockIdx.x*4 + (threadIdx.x >> 6);
  if (i >= *n_over) return;
  int e = over[i];
  int s = srcarr[(size_t)e*sstride], d = dstarr[(size_t)e*dstride];
  float f = 0.8f * w[e];
  float4 vv = ((const float4*)(Hin + (size_t)d*256))[lane];
  float* o = Hout + (size_t)s*256 + lane*4;
  atomicAdd(o+0, f*vv.x); atomicAdd(o+1, f*vv.y);
  atomicAdd(o+2, f*vv.z); atomicAdd(o+3, f*vv.w);
}

// ---------------- host launch ------------------------------------------------
extern "C" void kernel_launch(void* const* d_in, const int* in_sizes, int n_in,
                              void* d_out, int out_size, void* d_ws, size_t ws_size,
                              hipStream_t stream)
{
  const float* score = (const float*)d_in[0];
  const float* H0    = (const float*)d_in[1];
  const int*   edges0= (const int*)d_in[2];
  const int*   edges1= (const int*)d_in[3];
  const float* rel0  = (const float*)d_in[4];
  const float* rel1  = (const float*)d_in[5];
  const float* qst   = (const float*)d_in[6];
  const float* qr    = (const float*)d_in[7];
  const float* Wq    = (const float*)d_in[8];
  const float* Wk    = (const float*)d_in[9];
  const float* Wl    = (const float*)d_in[10];
  const float* bl    = (const float*)d_in[11];
  (void)in_sizes; (void)n_in; (void)out_size; (void)ws_size;

  float* out0 = (float*)d_out;
  float* out1 = out0 + NN;
  float* out2 = out1 + (size_t)NN*D;
  float* out3 = out2 + (size_t)NQ*ME*8;

  float* ws     = (float*)d_ws;
  float* Mbuf   = ws;                          // 1,048,576
  float* Ccat   = ws + 1048576;                // 128x1280 = 163,840
  float* qcv    = ws + 1212416;                // 128
  float* G      = ws + 1212544;                // 65,536
  float* logits = ws + 1278080;                // 32,768
  float* ebuf   = ws + 1310848;
  float* soft   = ws + 1343616;
  float* target = ws + 1376384;
  unsigned* menc= (unsigned*)(ws + 1409152);   // 50,000
  float* ssum   = ws + 1459152;                // 50,000
  int* p_src    = (int*)(ws + 1509152);        // 8,192
  int* p_dst    = (int*)(ws + 1517344);
  float* p_w    = ws + 1525536;                // ends 1,533,728
  float* Bq     = ws + 1533728;                // 512x1280 = 655,360 -> 2,189,088
  float* U      = ws + 2189088;                // 12,800,000 -> 14,989,088
  float* Hnew   = ws + 14989088;               // 12,800,000 -> 27,789,088
  float* SCR    = ws + 27789088;
  int* counts = (int*)SCR;                     // 50,000
  int* n_over = (int*)(SCR + 50000);           // 1
  int* over   = (int*)(SCR + 50056);           // 32,768
  int* bucket = (int*)(SCR + 100000);          // 1,600,000 -> SCR+1,700,000
  float* P0   = SCR + 2000000;                 // = ws + 29,789,088
  double* Mpart = (double*)P0;                 // 8M doubles = 16M floats (dead after reduce_m)
  f16* mhh_h  = (f16*)P0;                      // aliases Mpart (built after reduce_m)
  f16* mhh_l  = (f16*)(P0 + 32768);
  f16* wcat_h = (f16*)(P0 + 65536);
  f16* wcat_l = (f16*)(P0 + 163840);
  f16* wl_h   = (f16*)(P0 + 262144);
  f16* wl_l   = (f16*)(P0 + 294912);           // ends P0+327,680 (~186 MB total ws)
  float* Hpre = U;                             // alias: U dead before Hpre written

  hipMemsetAsync(out0, 0, (size_t)NN*4, stream);
  hipMemsetAsync(menc, 0, (size_t)NN*4, stream);
  hipMemsetAsync(ssum, 0, (size_t)NN*4, stream);

  // setup: M (fp64 split-K x8), query tables via GEMM, f16 B builders
  gemm_tn_split<<<dim3(16,16,8), 256, 0, stream>>>(Wq, Wk, Mpart);
  reduce_m<<<4096, 256, 0, stream>>>(Mpart, Mbuf);
  build_g<<<256, 256, 0, stream>>>(qst, qr, G);
  build_bq<<<2560, 256, 0, stream>>>(Mbuf, Bq);
  gemm64<<<dim3(2,20), 256, 0, stream>>>(G, 512, Bq, 1280, Ccat, 1280, NQ, 512);
  qc_dot<<<NQ, 256, 0, stream>>>(Ccat, qst, qr, qcv);
  build_bt_mhh<<<256, 256, 0, stream>>>(Mbuf, mhh_h, mhh_l);
  build_bt_wcat<<<768, 256, 0, stream>>>(Mbuf, wcat_h, wcat_l);
  split_f16<<<64, 256, 0, stream>>>(Wl, wl_h, wl_l, 65536);   // BT_wl == Wl

  // ---- call 1: edges1 / rel1 / H0 ----
  hgemm<0><<<dim3(391), 512, 0, stream>>>(H0, NN, mhh_h, mhh_l, U, 256, nullptr);
  slim_logits<<<NE/4, 256, 0, stream>>>(edges1, H0, U, rel1, Ccat, qcv, logits);
  hgemm_rel<<<dim3(256,3), 512, 0, stream>>>(rel1, wcat_h, wcat_l, edges1, H0, rel1, logits);

  segmax_k<<<NE/256, 256, 0, stream>>>(edges1, logits, menc, NE);
  segexp_k<<<NE/256, 256, 0, stream>>>(edges1, logits, menc, ebuf, ssum, NE);
  segsoft_k<1><<<NE/256, 256, 0, stream>>>(edges1, ebuf, ssum, soft, score, target, NE);

  topk_k<<<NQ, 256, 0, stream>>>(target, soft, edges1, out0, out2, out3, p_src, p_dst, p_w);

  hipMemsetAsync(counts, 0, (size_t)NN*4, stream);
  hipMemsetAsync(n_over, 0, 4, stream);
  bucket_fill<<<(NQ*ME+255)/256, 256, 0, stream>>>(p_src, 1, NQ*ME, counts, bucket, over, n_over);
  fused_update<<<(NN+3)/4, 256, 0, stream>>>(counts, bucket, p_dst, 1, p_w, H0, Hnew);
  over_k<<<(NQ*ME)/4, 256, 0, stream>>>(over, n_over, p_src, 1, p_dst, 1, p_w, H0, Hnew);

  hipMemsetAsync(menc, 0, (size_t)NN*4, stream);
  hipMemsetAsync(ssum, 0, (size_t)NN*4, stream);

  // ---- call 2: edges0 / rel0 / Hnew ----
  hgemm<0><<<dim3(391), 512, 0, stream>>>(Hnew, NN, mhh_h, mhh_l, U, 256, nullptr);
  slim_logits<<<NE/4, 256, 0, stream>>>(edges0, Hnew, U, rel0, Ccat, qcv, logits);
  hgemm_rel<<<dim3(256,3), 512, 0, stream>>>(rel0, wcat_h, wcat_l, edges0, Hnew, rel0, logits);

  segmax_k<<<NE/256, 256, 0, stream>>>(edges0, logits, menc, NE);
  segexp_k<<<NE/256, 256, 0, stream>>>(edges0, logits, menc, ebuf, ssum, NE);
  segsoft_k<0><<<NE/256, 256, 0, stream>>>(edges0, ebuf, ssum, soft, nullptr, nullptr, NE);

  hipMemsetAsync(counts, 0, (size_t)NN*4, stream);
  hipMemsetAsync(n_over, 0, 4, stream);
  bucket_fill<<<NE/256, 256, 0, stream>>>(edges0 + 6, 8, NE, counts, bucket, over, n_over);
  fused_update<<<(NN+3)/4, 256, 0, stream>>>(counts, bucket, edges0 + 7, 8, soft, Hnew, Hpre);
  over_k<<<NE/4, 256, 0, stream>>>(over, n_over, edges0 + 6, 8, edges0 + 7, 8, soft, Hnew, Hpre);

  // final: out1 = leaky_relu(Hpre @ Wl^T + bl)
  hgemm<1><<<dim3(391), 512, 0, stream>>>(Hpre, NN, wl_h, wl_l, out1, 256, bl);
}